// Round 13
// baseline (1105.354 us; speedup 1.0000x reference)
//
#include <hip/hip_runtime.h>

#define NF_ATOM 9
#define NF_BOND 3
#define DD 128
#define HH 256
#define NLAYER 5
#define NSHARD 32
#define NCODE 216
#define GRAM_NB 1024
#define GSHARD 16

typedef float fv4 __attribute__((ext_vector_type(4)));
typedef __bf16 bfv8 __attribute__((ext_vector_type(8)));
typedef unsigned int uv4 __attribute__((ext_vector_type(4)));

__device__ inline unsigned short f2bf(float f) {
    unsigned int u = __builtin_bit_cast(unsigned int, f);
    u = u + 0x7FFFu + ((u >> 16) & 1u);
    return (unsigned short)(u >> 16);
}
__device__ inline float bf2f(unsigned short s) {
    unsigned int u = ((unsigned int)s) << 16;
    return __builtin_bit_cast(float, u);
}

// ---------- atom encoder: h0 -> bf16 state ----------
__global__ __launch_bounds__(256) void k_atom(const int* __restrict__ x,
        const float* __restrict__ emb, unsigned short* __restrict__ h, int N) {
    int gid = blockIdx.x * 256 + threadIdx.x;
    int n = gid >> 5;
    if (n >= N) return;
    int c = (gid & 31) << 2;
    const int* xr = x + n * NF_ATOM;
    float4 acc = make_float4(0.f, 0.f, 0.f, 0.f);
#pragma unroll
    for (int f = 0; f < NF_ATOM; ++f) {
        int idx = xr[f];
        float4 v = *(const float4*)(emb + ((size_t)(f * 120 + idx) * DD) + c);
        acc.x += v.x; acc.y += v.y; acc.z += v.z; acc.w += v.w;
    }
    ushort4 o;
    o.x = f2bf(acc.x); o.y = f2bf(acc.y); o.z = f2bf(acc.z); o.w = f2bf(acc.w);
    *(ushort4*)(h + (size_t)n * DD + c) = o;
}

// ---------- weight convert: split bf16 (hi + residual lo), chunk-major ----------
// per-layer layout (shorts): [hi: 4|8 chunks][lo: 4|8 chunks], stride 65536
__global__ __launch_bounds__(256) void k_wconv(const float* __restrict__ W1,
        const float* __restrict__ W2, unsigned short* __restrict__ W1t,
        unsigned short* __restrict__ W2t) {
    int id = blockIdx.x * 256 + threadIdx.x;
    const int T1 = NLAYER * 4 * 256 * 32;      // 163840
    if (id < T1) {
        int k = id & 31, n = (id >> 5) & 255, kc = (id >> 13) & 3, l = id >> 15;
        int o = id & 32767;
        float w = W1[((size_t)(l * 128 + kc * 32 + k)) * 256 + n];
        unsigned short hi = f2bf(w);
        W1t[(size_t)l * 65536 + o] = hi;
        W1t[(size_t)l * 65536 + 32768 + o] = f2bf(w - bf2f(hi));
    } else {
        int id2 = id - T1;
        if (id2 >= NLAYER * 8 * 128 * 32) return;
        int k = id2 & 31, n = (id2 >> 5) & 127, kc = (id2 >> 12) & 7, l = id2 >> 15;
        int o = id2 & 32767;
        float w = W2[((size_t)(l * 256 + kc * 32 + k)) * 128 + n];
        unsigned short hi = f2bf(w);
        W2t[(size_t)l * 65536 + o] = hi;
        W2t[(size_t)l * 65536 + 32768 + o] = f2bf(w - bf2f(hi));
    }
}

// ---------- bond-sum table ----------
__global__ __launch_bounds__(256) void k_bsumtab(const float* __restrict__ bemb,
        float* __restrict__ tab) {
    int id = blockIdx.x * 256 + threadIdx.x;
    if (id >= NLAYER * NCODE * DD) return;
    int c = id & 127;
    int code = (id >> 7) % NCODE;
    int l = id / (NCODE * DD);
    int a0 = code % 6, a1 = (code / 6) % 6, a2 = code / 36;
    const float* bl = bemb + (size_t)l * NF_BOND * 6 * DD;
    tab[id] = bl[(0 * 6 + a0) * DD + c] + bl[(1 * 6 + a1) * DD + c] + bl[(2 * 6 + a2) * DD + c];
}

// ---------- CSR build ----------
__global__ __launch_bounds__(256) void k_deg(const int* __restrict__ ei, int* __restrict__ deg, int E) {
    int e = blockIdx.x * 256 + threadIdx.x;
    if (e < E) atomicAdd(&deg[ei[E + e]], 1);
}
__global__ __launch_bounds__(256) void k_bsum(const int* __restrict__ deg, int* __restrict__ bsum, int N) {
    __shared__ int red[256];
    int t = threadIdx.x, b = blockIdx.x;
    int i0 = b * 1024 + t * 4;
    int s = 0;
#pragma unroll
    for (int j = 0; j < 4; ++j) if (i0 + j < N) s += deg[i0 + j];
    red[t] = s; __syncthreads();
    for (int off = 128; off > 0; off >>= 1) {
        if (t < off) red[t] += red[t + off];
        __syncthreads();
    }
    if (t == 0) bsum[b] = red[0];
}
__global__ __launch_bounds__(256) void k_bscan(const int* __restrict__ bsum, int* __restrict__ boff, int nb) {
    __shared__ int ts[256];
    int t = threadIdx.x;
    int v = (t < nb) ? bsum[t] : 0;
    ts[t] = v; __syncthreads();
    for (int off = 1; off < 256; off <<= 1) {
        int u = (t >= off) ? ts[t - off] : 0;
        __syncthreads();
        ts[t] += u;
        __syncthreads();
    }
    if (t < nb) boff[t] = ts[t] - v;   // exclusive
}
__global__ __launch_bounds__(256) void k_csr(const int* deg, const int* __restrict__ boff,
        int* rs, int N, int E) {
    __shared__ int ts[256];
    int t = threadIdx.x, b = blockIdx.x;
    int i0 = b * 1024 + t * 4;
    int d[4];
#pragma unroll
    for (int j = 0; j < 4; ++j) d[j] = (i0 + j < N) ? deg[i0 + j] : 0;
    int tsum = d[0] + d[1] + d[2] + d[3];
    ts[t] = tsum; __syncthreads();
    for (int off = 1; off < 256; off <<= 1) {
        int u = (t >= off) ? ts[t - off] : 0;
        __syncthreads();
        ts[t] += u;
        __syncthreads();
    }
    int base = boff[b] + ts[t] - tsum;
    int p = 0;
#pragma unroll
    for (int j = 0; j < 4; ++j) {
        int dj = d[j];
        if (i0 + j < N) rs[i0 + j] = base + p;
        p += dj;
    }
    if (b == 0 && t == 0) rs[N] = E;
}
// packed record: src (18 bits) | code6 << 18
__global__ __launch_bounds__(256) void k_scatter(const int* __restrict__ ei,
        const int* __restrict__ ea, int* __restrict__ rs, int* __restrict__ epack, int E) {
    int e = blockIdx.x * 256 + threadIdx.x;
    if (e < E) {
        int pos = atomicAdd(&rs[ei[E + e]], 1);
        int code = ea[e * 3 + 0] + 6 * ea[e * 3 + 1] + 36 * ea[e * 3 + 2];
        epack[pos] = ei[e] | (code << 18);
    }
}

// ---------- BN2 shard reduce -> scale/shift ----------
__global__ void k_red(const float* __restrict__ sh, int C, const float* __restrict__ bng,
        const float* __restrict__ bnb, float invN,
        float* __restrict__ sc_out, float* __restrict__ sh_out) {
    int t = threadIdx.x;
    if (t >= C) return;
    float a = 0.f, qq = 0.f;
#pragma unroll
    for (int s = 0; s < NSHARD; ++s) {
        a += sh[s * 2 * C + t];
        qq += sh[s * 2 * C + C + t];
    }
    float mu = a * invN;
    float var = qq * invN - mu * mu;
    float r = rsqrtf(var + 1e-5f);
    float sc = bng[t] * r;
    sc_out[t] = sc; sh_out[t] = bnb[t] - mu * sc;
}

// ---------- zbuild ----------
__device__ inline void edge_acc(ushort4 hv, float4 bv, float4 sc, float4 sh, int mode, float* ag) {
    float h0 = bf2f(hv.x), h1 = bf2f(hv.y), h2 = bf2f(hv.z), h3 = bf2f(hv.w);
    if (mode) {
        h0 = fmaxf(h0 * sc.x + sh.x, 0.f); h1 = fmaxf(h1 * sc.y + sh.y, 0.f);
        h2 = fmaxf(h2 * sc.z + sh.z, 0.f); h3 = fmaxf(h3 * sc.w + sh.w, 0.f);
    }
    ag[0] += fmaxf(h0 + bv.x, 0.f); ag[1] += fmaxf(h1 + bv.y, 0.f);
    ag[2] += fmaxf(h2 + bv.z, 0.f); ag[3] += fmaxf(h3 + bv.w, 0.f);
}

__global__ __launch_bounds__(256) void k_zbuild(const unsigned short* __restrict__ y2h,
        const int* __restrict__ rs, const int* __restrict__ epack,
        const float* __restrict__ btab, const float* __restrict__ sctab,
        const float* __restrict__ shtab, const float* __restrict__ epsv,
        int l, int mode, unsigned short* __restrict__ z, int N) {
    int gid = blockIdx.x * 256 + threadIdx.x;
    int n = gid >> 5;
    if (n >= N) return;
    int c = (gid & 31) << 2;
    float4 sc4 = make_float4(1.f, 1.f, 1.f, 1.f), sh4 = make_float4(0.f, 0.f, 0.f, 0.f);
    if (mode) { sc4 = *(const float4*)(sctab + c); sh4 = *(const float4*)(shtab + c); }
    int p0 = (n == 0) ? 0 : rs[n - 1];
    int p1 = rs[n];
    float ag[4] = {0.f, 0.f, 0.f, 0.f};
    int p = p0;
    for (; p + 2 <= p1; p += 2) {
        int rec0 = epack[p], rec1 = epack[p + 1];
        int s0 = rec0 & 0x3FFFF, s1 = rec1 & 0x3FFFF;
        int c0 = ((unsigned int)rec0) >> 18, c1 = ((unsigned int)rec1) >> 18;
        ushort4 h0 = *(const ushort4*)(y2h + (size_t)s0 * DD + c);
        ushort4 h1 = *(const ushort4*)(y2h + (size_t)s1 * DD + c);
        float4 b0 = *(const float4*)(btab + (size_t)c0 * DD + c);
        float4 b1 = *(const float4*)(btab + (size_t)c1 * DD + c);
        edge_acc(h0, b0, sc4, sh4, mode, ag);
        edge_acc(h1, b1, sc4, sh4, mode, ag);
    }
    if (p < p1) {
        int rec = epack[p];
        int s0 = rec & 0x3FFFF;
        int c0 = ((unsigned int)rec) >> 18;
        ushort4 h0 = *(const ushort4*)(y2h + (size_t)s0 * DD + c);
        float4 b0 = *(const float4*)(btab + (size_t)c0 * DD + c);
        edge_acc(h0, b0, sc4, sh4, mode, ag);
    }
    float ep = 1.0f + epsv[l];
    ushort4 sv = *(const ushort4*)(y2h + (size_t)n * DD + c);
    float hz[4] = {bf2f(sv.x), bf2f(sv.y), bf2f(sv.z), bf2f(sv.w)};
    if (mode) {
        hz[0] = fmaxf(hz[0] * sc4.x + sh4.x, 0.f);
        hz[1] = fmaxf(hz[1] * sc4.y + sh4.y, 0.f);
        hz[2] = fmaxf(hz[2] * sc4.z + sh4.z, 0.f);
        hz[3] = fmaxf(hz[3] * sc4.w + sh4.w, 0.f);
    }
    ushort4 o;
    o.x = f2bf(ep * hz[0] + ag[0]);
    o.y = f2bf(ep * hz[1] + ag[1]);
    o.z = f2bf(ep * hz[2] + ag[2]);
    o.w = f2bf(ep * hz[3] + ag[3]);
    *(ushort4*)(z + (size_t)n * DD + c) = o;
}

// ---------- Gram: G = Z^T Z (128x128) + colsum(Z), sharded atomics ----------
// swizzle: slot(ch, g) = ch*8 + (g ^ ((ch ^ (ch>>3)) & 7))
__global__ __launch_bounds__(256) void k_gram(const unsigned short* __restrict__ z,
        float* __restrict__ shardG, float* __restrict__ csS, int N) {
    __shared__ uv4 zT[128 * 8];   // transposed tile [ch][8 granules of 8 rows], 16KB
    int tid = threadIdx.x;
    int lane = tid & 63, wave = tid >> 6, lq = lane >> 4, lr = lane & 15;
    int cg = tid & 15;            // channel-granule (8 ch) this thread stages
    float cs[8] = {0, 0, 0, 0, 0, 0, 0, 0};
    fv4 acc[2][8];
#pragma unroll
    for (int ti = 0; ti < 2; ++ti)
#pragma unroll
        for (int tj = 0; tj < 8; ++tj) acc[ti][tj] = (fv4){0.f, 0.f, 0.f, 0.f};

    int ntile = N >> 6;
    for (int t = blockIdx.x; t < ntile; t += GRAM_NB) {
        const unsigned short* zt0 = z + ((size_t)t << 6) * DD;
        __syncthreads();
#pragma unroll
        for (int i = 0; i < 2; ++i) {
            int rp = i * 16 + (tid >> 4);      // row pair index 0..31
            int r0 = rp * 2;
            uv4 a = *(const uv4*)(zt0 + (size_t)r0 * DD + cg * 8);
            uv4 b = *(const uv4*)(zt0 + (size_t)(r0 + 1) * DD + cg * 8);
            int g = rp >> 2;                   // granule along rows
            int eo = rp & 3;                   // u32 offset in granule
#pragma unroll
            for (int j = 0; j < 4; ++j) {
                unsigned int lo0 = a[j] & 0xFFFFu, hi0 = a[j] >> 16;
                unsigned int lo1 = b[j] & 0xFFFFu, hi1 = b[j] >> 16;
                cs[2 * j] += bf2f((unsigned short)lo0) + bf2f((unsigned short)lo1);
                cs[2 * j + 1] += bf2f((unsigned short)hi0) + bf2f((unsigned short)hi1);
                int ch0 = cg * 8 + 2 * j, ch1 = ch0 + 1;
                int s0 = ch0 * 8 + (g ^ ((ch0 ^ (ch0 >> 3)) & 7));
                int s1 = ch1 * 8 + (g ^ ((ch1 ^ (ch1 >> 3)) & 7));
                ((unsigned int*)zT)[s0 * 4 + eo] = lo0 | (lo1 << 16);
                ((unsigned int*)zT)[s1 * 4 + eo] = hi0 | (hi1 << 16);
            }
        }
        __syncthreads();
#pragma unroll
        for (int ks = 0; ks < 2; ++ks) {
            bfv8 af[2], bfr[8];
#pragma unroll
            for (int ti = 0; ti < 2; ++ti) {
                int ch = wave * 32 + ti * 16 + lr;
                af[ti] = __builtin_bit_cast(bfv8, zT[ch * 8 + ((ks * 4 + lq) ^ ((ch ^ (ch >> 3)) & 7))]);
            }
#pragma unroll
            for (int tj = 0; tj < 8; ++tj) {
                int ch = tj * 16 + lr;
                bfr[tj] = __builtin_bit_cast(bfv8, zT[ch * 8 + ((ks * 4 + lq) ^ ((ch ^ (ch >> 3)) & 7))]);
            }
#pragma unroll
            for (int ti = 0; ti < 2; ++ti)
#pragma unroll
                for (int tj = 0; tj < 8; ++tj)
                    acc[ti][tj] = __builtin_amdgcn_mfma_f32_16x16x32_bf16(af[ti], bfr[tj], acc[ti][tj], 0, 0, 0);
        }
    }
    // dump G shard
    float* gsh = shardG + (size_t)(blockIdx.x & (GSHARD - 1)) * (DD * DD);
#pragma unroll
    for (int ti = 0; ti < 2; ++ti) {
        int gi = wave * 32 + ti * 16 + lq * 4;
#pragma unroll
        for (int tj = 0; tj < 8; ++tj) {
            int gj = tj * 16 + lr;
#pragma unroll
            for (int r = 0; r < 4; ++r)
                atomicAdd(gsh + (size_t)(gi + r) * DD + gj, acc[ti][tj][r]);
        }
    }
    // colsum reduce in LDS, then sharded atomics
    __syncthreads();
    float* red = (float*)zT;
#pragma unroll
    for (int j = 0; j < 8; ++j) red[tid * 8 + j] = cs[j];
    __syncthreads();
    if (tid < 128) {
        int cgg = tid >> 3, j = tid & 7;
        float a = 0.f;
#pragma unroll
        for (int k = 0; k < 16; ++k) a += red[(k * 16 + cgg) * 8 + j];
        atomicAdd(csS + (blockIdx.x & (GSHARD - 1)) * DD + cgg * 8 + j, a);
    }
}

// ---------- reduce G/cs shards to dense ----------
__global__ __launch_bounds__(256) void k_gred(const float* __restrict__ shardG,
        const float* __restrict__ csS, float* __restrict__ G, float* __restrict__ cs) {
    int idx = blockIdx.x * 256 + threadIdx.x;
    if (idx < DD * DD) {
        float a = 0.f;
#pragma unroll
        for (int s = 0; s < GSHARD; ++s) a += shardG[s * DD * DD + idx];
        G[idx] = a;
    } else if (idx < DD * DD + DD) {
        int t = idx - DD * DD;
        float a = 0.f;
#pragma unroll
        for (int s = 0; s < GSHARD; ++s) a += csS[s * DD + t];
        cs[t] = a;
    }
}

// ---------- BN1 stats from Gram: per y1-col j -> sc1/sh1 (b1 folded into shift) ----------
// effective weight = W1hi + W1lo (matches fgemm's split MFMA)
__global__ __launch_bounds__(128) void k_redG(const float* __restrict__ G,
        const float* __restrict__ cs, const unsigned short* __restrict__ W1l,
        const float* __restrict__ b1, const float* __restrict__ bng,
        const float* __restrict__ bnb, float invN,
        float* __restrict__ sc_out, float* __restrict__ sh_out) {
    __shared__ float wv[128];
    __shared__ float redA[128], redB[128];
    int j = blockIdx.x;
    int t = threadIdx.x;
    int kc = t >> 5, kk = t & 31;
    int o = kc * 8192 + j * 32 + kk;
    float w_t = bf2f(W1l[o]) + bf2f(W1l[32768 + o]);
    wv[t] = w_t;
    __syncthreads();
    const float4* Gr = (const float4*)(G + (size_t)t * DD);
    float d = 0.f;
#pragma unroll
    for (int i = 0; i < 32; ++i) {
        float4 g4 = Gr[i];
        d += g4.x * wv[i * 4] + g4.y * wv[i * 4 + 1] + g4.z * wv[i * 4 + 2] + g4.w * wv[i * 4 + 3];
    }
    redA[t] = w_t * d;
    redB[t] = cs[t] * w_t;
    __syncthreads();
    for (int off = 64; off > 0; off >>= 1) {
        if (t < off) { redA[t] += redA[t + off]; redB[t] += redB[t + off]; }
        __syncthreads();
    }
    if (t == 0) {
        float bj = b1[j];
        float csw = redB[0];
        float mean = csw * invN + bj;
        float ey2 = redA[0] * invN + 2.f * bj * csw * invN + bj * bj;
        float var = ey2 - mean * mean;
        float r = rsqrtf(var + 1e-5f);
        float sc = bng[j] * r;
        sc_out[j] = sc;
        sh_out[j] = bnb[j] - mean * sc + bj * sc;   // b1 folded (fgemm acc excludes b1)
    }
}

// ---------- fused: y2h = bf16( relu(bn1(z@W1+b1)) @ W2 + b2 ), split weights ----------
// hi+lo chunks staged together per kc: 4 phase1 iters, 8 phase2 iters
__global__ __launch_bounds__(256) void k_fgemm(const unsigned short* __restrict__ z,
        const unsigned short* __restrict__ W1l, const unsigned short* __restrict__ W2l,
        const float* __restrict__ sc1, const float* __restrict__ sh1,
        const float* __restrict__ bias2,
        unsigned short* __restrict__ y2h, float* __restrict__ shard, int N) {
    __shared__ uv4 smem[3072];           // 48KB union
    uv4* zt = smem;                      // phase1: [64*16] 16KB
    uv4* wt = smem + 1024;               // phase1: hi[1024] lo[1024] 32KB
    uv4* at = smem;                      // phase2: [64*32] 32KB
    uv4* wt2 = smem + 2048;              // phase2: hi[512] lo[512] 16KB
    int tid = threadIdx.x;
    int row0 = blockIdx.x * 64;
    int wave = tid >> 6, lane = tid & 63, lq = lane >> 4, lr = lane & 15;
    int rbase = tid >> 4, gz = tid & 15;

    uv4 zr[4];
#pragma unroll
    for (int i = 0; i < 4; ++i)
        zr[i] = *(const uv4*)(z + (size_t)(row0 + i * 16 + rbase) * DD + gz * 8);
    const uv4* w1src = (const uv4*)W1l;      // hi chunks at kc*1024, lo at 4096+kc*1024
    uv4 wrh[4], wrl[4];
#pragma unroll
    for (int i = 0; i < 4; ++i) {
        wrh[i] = w1src[i * 256 + tid];
        wrl[i] = w1src[4096 + i * 256 + tid];
    }
#pragma unroll
    for (int i = 0; i < 4; ++i) {
        int row = i * 16 + rbase;
        zt[row * 16 + (gz ^ (row & 15))] = zr[i];
    }

    // phase 1: acc1[mc][nr] = (W1hi+W1lo)^T-tile x z-tile
    fv4 acc1[4][4];
#pragma unroll
    for (int mc = 0; mc < 4; ++mc)
#pragma unroll
        for (int nr = 0; nr < 4; ++nr) acc1[mc][nr] = (fv4){0.f, 0.f, 0.f, 0.f};

    for (int kc = 0; kc < 4; ++kc) {
        __syncthreads();
#pragma unroll
        for (int i = 0; i < 4; ++i) {
            int g = i * 256 + tid;
            int wn = g >> 2, gw = g & 3;
            int slot = wn * 4 + (gw ^ ((wn >> 1) & 3));
            wt[slot] = wrh[i];
            wt[1024 + slot] = wrl[i];
        }
        __syncthreads();
        if (kc < 3) {
#pragma unroll
            for (int i = 0; i < 4; ++i) {
                wrh[i] = w1src[(size_t)(kc + 1) * 1024 + i * 256 + tid];
                wrl[i] = w1src[4096 + (size_t)(kc + 1) * 1024 + i * 256 + tid];
            }
        }
        bfv8 wfh[4], wfl[4], zf[4];
#pragma unroll
        for (int mc = 0; mc < 4; ++mc) {
            int col = wave * 64 + mc * 16 + lr;
            int slot = col * 4 + (lq ^ ((col >> 1) & 3));
            wfh[mc] = __builtin_bit_cast(bfv8, wt[slot]);
            wfl[mc] = __builtin_bit_cast(bfv8, wt[1024 + slot]);
        }
#pragma unroll
        for (int nr = 0; nr < 4; ++nr) {
            int row = nr * 16 + lr;
            zf[nr] = __builtin_bit_cast(bfv8, zt[row * 16 + ((kc * 4 + lq) ^ (row & 15))]);
        }
#pragma unroll
        for (int mc = 0; mc < 4; ++mc)
#pragma unroll
            for (int nr = 0; nr < 4; ++nr) {
                acc1[mc][nr] = __builtin_amdgcn_mfma_f32_16x16x32_bf16(wfh[mc], zf[nr], acc1[mc][nr], 0, 0, 0);
                acc1[mc][nr] = __builtin_amdgcn_mfma_f32_16x16x32_bf16(wfl[mc], zf[nr], acc1[mc][nr], 0, 0, 0);
            }
    }
    __syncthreads();

    const uv4* w2src = (const uv4*)W2l;      // hi chunks at kc*512, lo at 4096+kc*512
    uv4 wr2h[2], wr2l[2];
    wr2h[0] = w2src[tid]; wr2h[1] = w2src[256 + tid];
    wr2l[0] = w2src[4096 + tid]; wr2l[1] = w2src[4096 + 256 + tid];

    // epilogue1: bn1-apply + relu + bf16 pack -> at tile
#pragma unroll
    for (int mc = 0; mc < 4; ++mc) {
        int ycol0 = wave * 64 + mc * 16 + lq * 4;
        float4 s4 = *(const float4*)(sc1 + ycol0);
        float4 h4 = *(const float4*)(sh1 + ycol0);
        int gg = wave * 8 + mc * 2 + (lq >> 1);
#pragma unroll
        for (int nr = 0; nr < 4; ++nr) {
            int zrow = nr * 16 + lr;
            float v0 = fmaxf(acc1[mc][nr][0] * s4.x + h4.x, 0.f);
            float v1 = fmaxf(acc1[mc][nr][1] * s4.y + h4.y, 0.f);
            float v2 = fmaxf(acc1[mc][nr][2] * s4.z + h4.z, 0.f);
            float v3 = fmaxf(acc1[mc][nr][3] * s4.w + h4.w, 0.f);
            uint2 pk;
            pk.x = (unsigned int)f2bf(v0) | ((unsigned int)f2bf(v1) << 16);
            pk.y = (unsigned int)f2bf(v2) | ((unsigned int)f2bf(v3) << 16);
            int gs = gg ^ (zrow & 15);
            ((uint2*)at)[(zrow * 32 + gs) * 2 + (lq & 1)] = pk;
        }
    }

    // phase 2: y2 = at @ (W2hi+W2lo)
    fv4 acc2[4][2];
#pragma unroll
    for (int m = 0; m < 4; ++m) { acc2[m][0] = (fv4){0.f,0.f,0.f,0.f}; acc2[m][1] = (fv4){0.f,0.f,0.f,0.f}; }

    for (int kc = 0; kc < 8; ++kc) {
        __syncthreads();
        {
            int wn = tid >> 2, gw = tid & 3;
            int slot = wn * 4 + (gw ^ ((wn >> 1) & 3));
            wt2[slot] = wr2h[0];
            wt2[512 + slot] = wr2l[0];
            int g3 = 256 + tid, wn3 = g3 >> 2, gw3 = g3 & 3;
            int slot3 = wn3 * 4 + (gw3 ^ ((wn3 >> 1) & 3));
            wt2[slot3] = wr2h[1];
            wt2[512 + slot3] = wr2l[1];
        }
        __syncthreads();
        if (kc < 7) {
            wr2h[0] = w2src[(size_t)(kc + 1) * 512 + tid];
            wr2h[1] = w2src[(size_t)(kc + 1) * 512 + 256 + tid];
            wr2l[0] = w2src[4096 + (size_t)(kc + 1) * 512 + tid];
            wr2l[1] = w2src[4096 + (size_t)(kc + 1) * 512 + 256 + tid];
        }
        bfv8 a[4], bh[2], bl[2];
#pragma unroll
        for (int m = 0; m < 4; ++m) {
            int row = m * 16 + lr;
            a[m] = __builtin_bit_cast(bfv8, at[row * 32 + ((kc * 4 + lq) ^ (row & 15))]);
        }
#pragma unroll
        for (int nb = 0; nb < 2; ++nb) {
            int col = wave * 32 + nb * 16 + lr;
            int slot = col * 4 + (lq ^ ((col >> 1) & 3));
            bh[nb] = __builtin_bit_cast(bfv8, wt2[slot]);
            bl[nb] = __builtin_bit_cast(bfv8, wt2[512 + slot]);
        }
#pragma unroll
        for (int m = 0; m < 4; ++m)
#pragma unroll
            for (int nb = 0; nb < 2; ++nb) {
                acc2[m][nb] = __builtin_amdgcn_mfma_f32_16x16x32_bf16(a[m], bh[nb], acc2[m][nb], 0, 0, 0);
                acc2[m][nb] = __builtin_amdgcn_mfma_f32_16x16x32_bf16(a[m], bl[nb], acc2[m][nb], 0, 0, 0);
            }
    }

    float bv[2], s[2], q[2];
#pragma unroll
    for (int nb = 0; nb < 2; ++nb) {
        bv[nb] = bias2[wave * 32 + nb * 16 + lr];
        s[nb] = 0.f; q[nb] = 0.f;
    }
#pragma unroll
    for (int m = 0; m < 4; ++m)
#pragma unroll
        for (int nb = 0; nb < 2; ++nb) {
            int col = wave * 32 + nb * 16 + lr;
#pragma unroll
            for (int r = 0; r < 4; ++r) {
                float v = acc2[m][nb][r] + bv[nb];
                unsigned short ub = f2bf(v);
                float vr = bf2f(ub);
                int row = row0 + m * 16 + lq * 4 + r;
                y2h[(size_t)row * DD + col] = ub;
                s[nb] += vr; q[nb] += vr * vr;
            }
        }
#pragma unroll
    for (int nb = 0; nb < 2; ++nb) {
        s[nb] += __shfl_xor(s[nb], 16); s[nb] += __shfl_xor(s[nb], 32);
        q[nb] += __shfl_xor(q[nb], 16); q[nb] += __shfl_xor(q[nb], 32);
    }
    if (lane < 16) {
        int shb = (blockIdx.x & (NSHARD - 1)) * 256;
#pragma unroll
        for (int nb = 0; nb < 2; ++nb) {
            int col = wave * 32 + nb * 16 + lr;
            atomicAdd(shard + shb + col, s[nb]);
            atomicAdd(shard + shb + 128 + col, q[nb]);
        }
    }
}

// ---------- final: out = relu(bn2(y2h)) -> f32 ----------
__global__ __launch_bounds__(256) void k_bnfinal(const unsigned short* __restrict__ y2h,
        const float* __restrict__ sc2, const float* __restrict__ sh2,
        float* __restrict__ out, int N) {
    size_t base = ((size_t)blockIdx.x * 256 + threadIdx.x) * 4;
    if (base >= (size_t)N * DD) return;
    int c = (int)(base & (DD - 1));
    ushort4 v = *(const ushort4*)(y2h + base);
    float4 s = *(const float4*)(sc2 + c);
    float4 t = *(const float4*)(sh2 + c);
    float4 o;
    o.x = fmaxf(bf2f(v.x) * s.x + t.x, 0.f);
    o.y = fmaxf(bf2f(v.y) * s.y + t.y, 0.f);
    o.z = fmaxf(bf2f(v.z) * s.z + t.z, 0.f);
    o.w = fmaxf(bf2f(v.w) * s.w + t.w, 0.f);
    *(float4*)(out + base) = o;
}

extern "C" void kernel_launch(void* const* d_in, const int* in_sizes, int n_in,
                              void* d_out, int out_size, void* d_ws, size_t ws_size,
                              hipStream_t stream) {
    const int* x = (const int*)d_in[0];
    const int* ei = (const int*)d_in[1];
    const int* ea = (const int*)d_in[2];
    const float* atom_emb = (const float*)d_in[3];
    const float* bond_emb = (const float*)d_in[4];
    const float* W1 = (const float*)d_in[5];
    const float* b1 = (const float*)d_in[6];
    const float* bn1_g = (const float*)d_in[7];
    const float* bn1_b = (const float*)d_in[8];
    const float* W2 = (const float*)d_in[9];
    const float* b2 = (const float*)d_in[10];
    const float* epsv = (const float*)d_in[11];
    const float* obn_g = (const float*)d_in[12];
    const float* obn_b = (const float*)d_in[13];
    int N = in_sizes[0] / NF_ATOM;   // 200000 (divisible by 64)
    int E = in_sizes[1] / 2;

    char* wsb = (char*)d_ws;
    unsigned short* y2h = (unsigned short*)wsb;                        // N*128 bf16
    unsigned short* zb = (unsigned short*)(wsb + (size_t)N * 256);     // N*128 bf16
    int* epack = (int*)(wsb + (size_t)N * 512);                        // E int
    unsigned short* w1t = (unsigned short*)(wsb + (size_t)N * 512 + (size_t)E * 4);  // 5*65536
    unsigned short* w2t = w1t + 327680;                                // 5*65536
    float* btab = (float*)((char*)w2t + 655360);                       // 5*216*128 f32
    float* sc1 = btab + NLAYER * NCODE * DD;                           // 256
    float* sh1 = sc1 + 256;
    float* sc2 = sh1 + 256;                                            // 128
    float* sh2 = sc2 + 128;
    float* G = sh2 + 128;                                              // 16384
    float* cs = G + DD * DD;                                           // 128
    float* shardbase = cs + DD;                                        // zero region start
    float* shardG = shardbase;                                         // 5 * 16*16384
    float* csS = shardG + (size_t)NLAYER * GSHARD * DD * DD;           // 5 * 16*128
    float* shard2 = csS + NLAYER * GSHARD * DD;                        // 5 * 32*256
    size_t zero_f = (size_t)NLAYER * (GSHARD * DD * DD + GSHARD * DD + NSHARD * 256);
    int* rsarr = (int*)(shard2 + (size_t)NLAYER * NSHARD * 256);       // N+1
    int* bsum = rsarr + (N + 1);
    int* boff = bsum + 256;
    float invN = 1.0f / (float)N;
    int nbk = (N + 1023) / 1024;

    k_wconv<<<1280, 256, 0, stream>>>(W1, W2, w1t, w2t);
    k_bsumtab<<<(NLAYER * NCODE * DD + 255) / 256, 256, 0, stream>>>(bond_emb, btab);
    hipMemsetAsync(rsarr, 0, ((size_t)N + 1) * 4, stream);
    hipMemsetAsync(shardbase, 0, zero_f * sizeof(float), stream);
    k_deg<<<(E + 255) / 256, 256, 0, stream>>>(ei, rsarr, E);
    k_bsum<<<nbk, 256, 0, stream>>>(rsarr, bsum, N);
    k_bscan<<<1, 256, 0, stream>>>(bsum, boff, nbk);
    k_csr<<<nbk, 256, 0, stream>>>(rsarr, boff, rsarr, N, E);
    k_scatter<<<(E + 255) / 256, 256, 0, stream>>>(ei, ea, rsarr, epack, E);
    k_atom<<<(N * 32 + 255) / 256, 256, 0, stream>>>(x, atom_emb, y2h, N);

    int gb = N / 64;
    for (int l = 0; l < NLAYER; ++l) {
        float* shG = shardG + (size_t)l * GSHARD * DD * DD;
        float* shc = csS + (size_t)l * GSHARD * DD;
        float* sh2d = shard2 + (size_t)l * NSHARD * 256;
        k_zbuild<<<(N * 32 + 255) / 256, 256, 0, stream>>>(y2h, rsarr, epack,
                btab + (size_t)l * NCODE * DD, sc2, sh2, epsv, l, (l == 0) ? 0 : 1, zb, N);
        k_gram<<<GRAM_NB, 256, 0, stream>>>(zb, shG, shc, N);
        k_gred<<<(DD * DD + DD + 255) / 256, 256, 0, stream>>>(shG, shc, G, cs);
        k_redG<<<HH, 128, 0, stream>>>(G, cs, w1t + (size_t)l * 65536, b1 + l * HH,
                bn1_g + l * HH, bn1_b + l * HH, invN, sc1, sh1);
        k_fgemm<<<gb, 256, 0, stream>>>(zb, w1t + (size_t)l * 65536, w2t + (size_t)l * 65536,
                sc1, sh1, b2 + l * DD, y2h, sh2d, N);
        k_red<<<1, 128, 0, stream>>>(sh2d, 128, obn_g + l * DD, obn_b + l * DD, invN, sc2, sh2);
    }
    k_bnfinal<<<(int)(((size_t)N * DD / 4 + 255) / 256), 256, 0, stream>>>(
            y2h, sc2, sh2, (float*)d_out, N);
}

// Round 14
// 929.145 us; speedup vs baseline: 1.1896x; 1.1896x over previous
//
#include <hip/hip_runtime.h>

#define NF_ATOM 9
#define NF_BOND 3
#define DD 128
#define HH 256
#define NLAYER 5
#define NSHARD 32
#define NCODE 216
#define GRAM_NB 256

typedef float fv4 __attribute__((ext_vector_type(4)));
typedef __bf16 bfv8 __attribute__((ext_vector_type(8)));
typedef unsigned int uv4 __attribute__((ext_vector_type(4)));

__device__ inline unsigned short f2bf(float f) {
    unsigned int u = __builtin_bit_cast(unsigned int, f);
    u = u + 0x7FFFu + ((u >> 16) & 1u);
    return (unsigned short)(u >> 16);
}
__device__ inline float bf2f(unsigned short s) {
    unsigned int u = ((unsigned int)s) << 16;
    return __builtin_bit_cast(float, u);
}

// ---------- atom encoder: h0 -> bf16 state ----------
__global__ __launch_bounds__(256) void k_atom(const int* __restrict__ x,
        const float* __restrict__ emb, unsigned short* __restrict__ h, int N) {
    int gid = blockIdx.x * 256 + threadIdx.x;
    int n = gid >> 5;
    if (n >= N) return;
    int c = (gid & 31) << 2;
    const int* xr = x + n * NF_ATOM;
    float4 acc = make_float4(0.f, 0.f, 0.f, 0.f);
#pragma unroll
    for (int f = 0; f < NF_ATOM; ++f) {
        int idx = xr[f];
        float4 v = *(const float4*)(emb + ((size_t)(f * 120 + idx) * DD) + c);
        acc.x += v.x; acc.y += v.y; acc.z += v.z; acc.w += v.w;
    }
    ushort4 o;
    o.x = f2bf(acc.x); o.y = f2bf(acc.y); o.z = f2bf(acc.z); o.w = f2bf(acc.w);
    *(ushort4*)(h + (size_t)n * DD + c) = o;
}

// ---------- weight convert: split bf16 (hi + residual lo), chunk-major ----------
__global__ __launch_bounds__(256) void k_wconv(const float* __restrict__ W1,
        const float* __restrict__ W2, unsigned short* __restrict__ W1t,
        unsigned short* __restrict__ W2t) {
    int id = blockIdx.x * 256 + threadIdx.x;
    const int T1 = NLAYER * 4 * 256 * 32;      // 163840
    if (id < T1) {
        int k = id & 31, n = (id >> 5) & 255, kc = (id >> 13) & 3, l = id >> 15;
        int o = id & 32767;
        float w = W1[((size_t)(l * 128 + kc * 32 + k)) * 256 + n];
        unsigned short hi = f2bf(w);
        W1t[(size_t)l * 65536 + o] = hi;
        W1t[(size_t)l * 65536 + 32768 + o] = f2bf(w - bf2f(hi));
    } else {
        int id2 = id - T1;
        if (id2 >= NLAYER * 8 * 128 * 32) return;
        int k = id2 & 31, n = (id2 >> 5) & 127, kc = (id2 >> 12) & 7, l = id2 >> 15;
        int o = id2 & 32767;
        float w = W2[((size_t)(l * 256 + kc * 32 + k)) * 128 + n];
        unsigned short hi = f2bf(w);
        W2t[(size_t)l * 65536 + o] = hi;
        W2t[(size_t)l * 65536 + 32768 + o] = f2bf(w - bf2f(hi));
    }
}

// ---------- bond-sum table ----------
__global__ __launch_bounds__(256) void k_bsumtab(const float* __restrict__ bemb,
        float* __restrict__ tab) {
    int id = blockIdx.x * 256 + threadIdx.x;
    if (id >= NLAYER * NCODE * DD) return;
    int c = id & 127;
    int code = (id >> 7) % NCODE;
    int l = id / (NCODE * DD);
    int a0 = code % 6, a1 = (code / 6) % 6, a2 = code / 36;
    const float* bl = bemb + (size_t)l * NF_BOND * 6 * DD;
    tab[id] = bl[(0 * 6 + a0) * DD + c] + bl[(1 * 6 + a1) * DD + c] + bl[(2 * 6 + a2) * DD + c];
}

// ---------- CSR build ----------
__global__ __launch_bounds__(256) void k_deg(const int* __restrict__ ei, int* __restrict__ deg, int E) {
    int e = blockIdx.x * 256 + threadIdx.x;
    if (e < E) atomicAdd(&deg[ei[E + e]], 1);
}
__global__ __launch_bounds__(256) void k_bsum(const int* __restrict__ deg, int* __restrict__ bsum, int N) {
    __shared__ int red[256];
    int t = threadIdx.x, b = blockIdx.x;
    int i0 = b * 1024 + t * 4;
    int s = 0;
#pragma unroll
    for (int j = 0; j < 4; ++j) if (i0 + j < N) s += deg[i0 + j];
    red[t] = s; __syncthreads();
    for (int off = 128; off > 0; off >>= 1) {
        if (t < off) red[t] += red[t + off];
        __syncthreads();
    }
    if (t == 0) bsum[b] = red[0];
}
__global__ __launch_bounds__(256) void k_bscan(const int* __restrict__ bsum, int* __restrict__ boff, int nb) {
    __shared__ int ts[256];
    int t = threadIdx.x;
    int v = (t < nb) ? bsum[t] : 0;
    ts[t] = v; __syncthreads();
    for (int off = 1; off < 256; off <<= 1) {
        int u = (t >= off) ? ts[t - off] : 0;
        __syncthreads();
        ts[t] += u;
        __syncthreads();
    }
    if (t < nb) boff[t] = ts[t] - v;   // exclusive
}
__global__ __launch_bounds__(256) void k_csr(const int* deg, const int* __restrict__ boff,
        int* rs, int N, int E) {
    __shared__ int ts[256];
    int t = threadIdx.x, b = blockIdx.x;
    int i0 = b * 1024 + t * 4;
    int d[4];
#pragma unroll
    for (int j = 0; j < 4; ++j) d[j] = (i0 + j < N) ? deg[i0 + j] : 0;
    int tsum = d[0] + d[1] + d[2] + d[3];
    ts[t] = tsum; __syncthreads();
    for (int off = 1; off < 256; off <<= 1) {
        int u = (t >= off) ? ts[t - off] : 0;
        __syncthreads();
        ts[t] += u;
        __syncthreads();
    }
    int base = boff[b] + ts[t] - tsum;
    int p = 0;
#pragma unroll
    for (int j = 0; j < 4; ++j) {
        int dj = d[j];
        if (i0 + j < N) rs[i0 + j] = base + p;
        p += dj;
    }
    if (b == 0 && t == 0) rs[N] = E;
}
// packed record: src (18 bits) | code6 << 18
__global__ __launch_bounds__(256) void k_scatter(const int* __restrict__ ei,
        const int* __restrict__ ea, int* __restrict__ rs, int* __restrict__ epack, int E) {
    int e = blockIdx.x * 256 + threadIdx.x;
    if (e < E) {
        int pos = atomicAdd(&rs[ei[E + e]], 1);
        int code = ea[e * 3 + 0] + 6 * ea[e * 3 + 1] + 36 * ea[e * 3 + 2];
        epack[pos] = ei[e] | (code << 18);
    }
}

// ---------- BN2 shard reduce -> scale/shift ----------
__global__ void k_red(const float* __restrict__ sh, int C, const float* __restrict__ bng,
        const float* __restrict__ bnb, float invN,
        float* __restrict__ sc_out, float* __restrict__ sh_out) {
    int t = threadIdx.x;
    if (t >= C) return;
    float a = 0.f, qq = 0.f;
#pragma unroll
    for (int s = 0; s < NSHARD; ++s) {
        a += sh[s * 2 * C + t];
        qq += sh[s * 2 * C + C + t];
    }
    float mu = a * invN;
    float var = qq * invN - mu * mu;
    float r = rsqrtf(var + 1e-5f);
    float sc = bng[t] * r;
    sc_out[t] = sc; sh_out[t] = bnb[t] - mu * sc;
}

// ---------- zbuild ----------
__device__ inline void edge_acc(ushort4 hv, float4 bv, float4 sc, float4 sh, int mode, float* ag) {
    float h0 = bf2f(hv.x), h1 = bf2f(hv.y), h2 = bf2f(hv.z), h3 = bf2f(hv.w);
    if (mode) {
        h0 = fmaxf(h0 * sc.x + sh.x, 0.f); h1 = fmaxf(h1 * sc.y + sh.y, 0.f);
        h2 = fmaxf(h2 * sc.z + sh.z, 0.f); h3 = fmaxf(h3 * sc.w + sh.w, 0.f);
    }
    ag[0] += fmaxf(h0 + bv.x, 0.f); ag[1] += fmaxf(h1 + bv.y, 0.f);
    ag[2] += fmaxf(h2 + bv.z, 0.f); ag[3] += fmaxf(h3 + bv.w, 0.f);
}

__global__ __launch_bounds__(256) void k_zbuild(const unsigned short* __restrict__ y2h,
        const int* __restrict__ rs, const int* __restrict__ epack,
        const float* __restrict__ btab, const float* __restrict__ sctab,
        const float* __restrict__ shtab, const float* __restrict__ epsv,
        int l, int mode, unsigned short* __restrict__ z, int N) {
    int gid = blockIdx.x * 256 + threadIdx.x;
    int n = gid >> 5;
    if (n >= N) return;
    int c = (gid & 31) << 2;
    float4 sc4 = make_float4(1.f, 1.f, 1.f, 1.f), sh4 = make_float4(0.f, 0.f, 0.f, 0.f);
    if (mode) { sc4 = *(const float4*)(sctab + c); sh4 = *(const float4*)(shtab + c); }
    int p0 = (n == 0) ? 0 : rs[n - 1];
    int p1 = rs[n];
    float ag[4] = {0.f, 0.f, 0.f, 0.f};
    int p = p0;
    for (; p + 2 <= p1; p += 2) {
        int rec0 = epack[p], rec1 = epack[p + 1];
        int s0 = rec0 & 0x3FFFF, s1 = rec1 & 0x3FFFF;
        int c0 = ((unsigned int)rec0) >> 18, c1 = ((unsigned int)rec1) >> 18;
        ushort4 h0 = *(const ushort4*)(y2h + (size_t)s0 * DD + c);
        ushort4 h1 = *(const ushort4*)(y2h + (size_t)s1 * DD + c);
        float4 b0 = *(const float4*)(btab + (size_t)c0 * DD + c);
        float4 b1 = *(const float4*)(btab + (size_t)c1 * DD + c);
        edge_acc(h0, b0, sc4, sh4, mode, ag);
        edge_acc(h1, b1, sc4, sh4, mode, ag);
    }
    if (p < p1) {
        int rec = epack[p];
        int s0 = rec & 0x3FFFF;
        int c0 = ((unsigned int)rec) >> 18;
        ushort4 h0 = *(const ushort4*)(y2h + (size_t)s0 * DD + c);
        float4 b0 = *(const float4*)(btab + (size_t)c0 * DD + c);
        edge_acc(h0, b0, sc4, sh4, mode, ag);
    }
    float ep = 1.0f + epsv[l];
    ushort4 sv = *(const ushort4*)(y2h + (size_t)n * DD + c);
    float hz[4] = {bf2f(sv.x), bf2f(sv.y), bf2f(sv.z), bf2f(sv.w)};
    if (mode) {
        hz[0] = fmaxf(hz[0] * sc4.x + sh4.x, 0.f);
        hz[1] = fmaxf(hz[1] * sc4.y + sh4.y, 0.f);
        hz[2] = fmaxf(hz[2] * sc4.z + sh4.z, 0.f);
        hz[3] = fmaxf(hz[3] * sc4.w + sh4.w, 0.f);
    }
    ushort4 o;
    o.x = f2bf(ep * hz[0] + ag[0]);
    o.y = f2bf(ep * hz[1] + ag[1]);
    o.z = f2bf(ep * hz[2] + ag[2]);
    o.w = f2bf(ep * hz[3] + ag[3]);
    *(ushort4*)(z + (size_t)n * DD + c) = o;
}

// ---------- Gram: per-block partial G = Z^T Z + colsum, direct stores (no atomics) ----------
// swizzle: slot(ch, g) = ch*8 + (g ^ ((ch ^ (ch>>3)) & 7))
__global__ __launch_bounds__(256) void k_gram(const unsigned short* __restrict__ z,
        float* __restrict__ shardG, float* __restrict__ csS, int N) {
    __shared__ uv4 zT[128 * 8];   // transposed tile [ch][8 granules of 8 rows], 16KB
    int tid = threadIdx.x;
    int lane = tid & 63, wave = tid >> 6, lq = lane >> 4, lr = lane & 15;
    int cg = tid & 15;            // channel-granule (8 ch) this thread stages
    float cs[8] = {0, 0, 0, 0, 0, 0, 0, 0};
    fv4 acc[2][8];
#pragma unroll
    for (int ti = 0; ti < 2; ++ti)
#pragma unroll
        for (int tj = 0; tj < 8; ++tj) acc[ti][tj] = (fv4){0.f, 0.f, 0.f, 0.f};

    int ntile = N >> 6;
    for (int t = blockIdx.x; t < ntile; t += GRAM_NB) {
        const unsigned short* zt0 = z + ((size_t)t << 6) * DD;
        __syncthreads();
#pragma unroll
        for (int i = 0; i < 2; ++i) {
            int rp = i * 16 + (tid >> 4);      // row pair index 0..31
            int r0 = rp * 2;
            uv4 a = *(const uv4*)(zt0 + (size_t)r0 * DD + cg * 8);
            uv4 b = *(const uv4*)(zt0 + (size_t)(r0 + 1) * DD + cg * 8);
            int g = rp >> 2;
            int eo = rp & 3;
#pragma unroll
            for (int j = 0; j < 4; ++j) {
                unsigned int lo0 = a[j] & 0xFFFFu, hi0 = a[j] >> 16;
                unsigned int lo1 = b[j] & 0xFFFFu, hi1 = b[j] >> 16;
                cs[2 * j] += bf2f((unsigned short)lo0) + bf2f((unsigned short)lo1);
                cs[2 * j + 1] += bf2f((unsigned short)hi0) + bf2f((unsigned short)hi1);
                int ch0 = cg * 8 + 2 * j, ch1 = ch0 + 1;
                int s0 = ch0 * 8 + (g ^ ((ch0 ^ (ch0 >> 3)) & 7));
                int s1 = ch1 * 8 + (g ^ ((ch1 ^ (ch1 >> 3)) & 7));
                ((unsigned int*)zT)[s0 * 4 + eo] = lo0 | (lo1 << 16);
                ((unsigned int*)zT)[s1 * 4 + eo] = hi0 | (hi1 << 16);
            }
        }
        __syncthreads();
#pragma unroll
        for (int ks = 0; ks < 2; ++ks) {
            bfv8 af[2], bfr[8];
#pragma unroll
            for (int ti = 0; ti < 2; ++ti) {
                int ch = wave * 32 + ti * 16 + lr;
                af[ti] = __builtin_bit_cast(bfv8, zT[ch * 8 + ((ks * 4 + lq) ^ ((ch ^ (ch >> 3)) & 7))]);
            }
#pragma unroll
            for (int tj = 0; tj < 8; ++tj) {
                int ch = tj * 16 + lr;
                bfr[tj] = __builtin_bit_cast(bfv8, zT[ch * 8 + ((ks * 4 + lq) ^ ((ch ^ (ch >> 3)) & 7))]);
            }
#pragma unroll
            for (int ti = 0; ti < 2; ++ti)
#pragma unroll
                for (int tj = 0; tj < 8; ++tj)
                    acc[ti][tj] = __builtin_amdgcn_mfma_f32_16x16x32_bf16(af[ti], bfr[tj], acc[ti][tj], 0, 0, 0);
        }
    }
    // store partial G (each thread owns 64 distinct cells; union covers 128x128)
    float* gsh = shardG + (size_t)blockIdx.x * (DD * DD);
#pragma unroll
    for (int ti = 0; ti < 2; ++ti) {
        int gi = wave * 32 + ti * 16 + lq * 4;
#pragma unroll
        for (int tj = 0; tj < 8; ++tj) {
            int gj = tj * 16 + lr;
#pragma unroll
            for (int r = 0; r < 4; ++r)
                gsh[(size_t)(gi + r) * DD + gj] = acc[ti][tj][r];
        }
    }
    // colsum reduce in LDS, direct store
    __syncthreads();
    float* red = (float*)zT;
#pragma unroll
    for (int j = 0; j < 8; ++j) red[tid * 8 + j] = cs[j];
    __syncthreads();
    if (tid < 128) {
        int cgg = tid >> 3, j = tid & 7;
        float a = 0.f;
#pragma unroll
        for (int k = 0; k < 16; ++k) a += red[(k * 16 + cgg) * 8 + j];
        csS[blockIdx.x * DD + cgg * 8 + j] = a;
    }
}

// ---------- reduce G/cs shards to dense ----------
__global__ __launch_bounds__(256) void k_gred(const float* __restrict__ shardG,
        const float* __restrict__ csS, float* __restrict__ G, float* __restrict__ cs) {
    int idx = blockIdx.x * 256 + threadIdx.x;
    if (idx < DD * DD) {
        float a = 0.f;
#pragma unroll 8
        for (int s = 0; s < GRAM_NB; ++s) a += shardG[(size_t)s * DD * DD + idx];
        G[idx] = a;
    } else if (idx < DD * DD + DD) {
        int t = idx - DD * DD;
        float a = 0.f;
#pragma unroll 8
        for (int s = 0; s < GRAM_NB; ++s) a += csS[s * DD + t];
        cs[t] = a;
    }
}

// ---------- BN1 stats from Gram: per y1-col j -> sc1/sh1 (b1 folded into shift) ----------
__global__ __launch_bounds__(128) void k_redG(const float* __restrict__ G,
        const float* __restrict__ cs, const unsigned short* __restrict__ W1l,
        const float* __restrict__ b1, const float* __restrict__ bng,
        const float* __restrict__ bnb, float invN,
        float* __restrict__ sc_out, float* __restrict__ sh_out) {
    __shared__ float wv[128];
    __shared__ float redA[128], redB[128];
    int j = blockIdx.x;
    int t = threadIdx.x;
    int kc = t >> 5, kk = t & 31;
    int o = kc * 8192 + j * 32 + kk;
    float w_t = bf2f(W1l[o]) + bf2f(W1l[32768 + o]);
    wv[t] = w_t;
    __syncthreads();
    const float4* Gr = (const float4*)(G + (size_t)t * DD);
    float d = 0.f;
#pragma unroll
    for (int i = 0; i < 32; ++i) {
        float4 g4 = Gr[i];
        d += g4.x * wv[i * 4] + g4.y * wv[i * 4 + 1] + g4.z * wv[i * 4 + 2] + g4.w * wv[i * 4 + 3];
    }
    redA[t] = w_t * d;
    redB[t] = cs[t] * w_t;
    __syncthreads();
    for (int off = 64; off > 0; off >>= 1) {
        if (t < off) { redA[t] += redA[t + off]; redB[t] += redB[t + off]; }
        __syncthreads();
    }
    if (t == 0) {
        float bj = b1[j];
        float csw = redB[0];
        float mean = csw * invN + bj;
        float ey2 = redA[0] * invN + 2.f * bj * csw * invN + bj * bj;
        float var = ey2 - mean * mean;
        float r = rsqrtf(var + 1e-5f);
        float sc = bng[j] * r;
        sc_out[j] = sc;
        sh_out[j] = bnb[j] - mean * sc + bj * sc;   // b1 folded (fgemm acc excludes b1)
    }
}

// ---------- fused: y2h = bf16( relu(bn1(z@W1+b1)) @ W2 + b2 ), split weights ----------
__global__ __launch_bounds__(256) void k_fgemm(const unsigned short* __restrict__ z,
        const unsigned short* __restrict__ W1l, const unsigned short* __restrict__ W2l,
        const float* __restrict__ sc1, const float* __restrict__ sh1,
        const float* __restrict__ bias2,
        unsigned short* __restrict__ y2h, float* __restrict__ shard, int N) {
    __shared__ uv4 smem[3072];           // 48KB union
    uv4* zt = smem;                      // phase1: [64*16] 16KB
    uv4* wt = smem + 1024;               // phase1: hi[1024] lo[1024] 32KB
    uv4* at = smem;                      // phase2: [64*32] 32KB
    uv4* wt2 = smem + 2048;              // phase2: hi[512] lo[512] 16KB
    int tid = threadIdx.x;
    int row0 = blockIdx.x * 64;
    int wave = tid >> 6, lane = tid & 63, lq = lane >> 4, lr = lane & 15;
    int rbase = tid >> 4, gz = tid & 15;

    uv4 zr[4];
#pragma unroll
    for (int i = 0; i < 4; ++i)
        zr[i] = *(const uv4*)(z + (size_t)(row0 + i * 16 + rbase) * DD + gz * 8);
    const uv4* w1src = (const uv4*)W1l;      // hi chunks at kc*1024, lo at 4096+kc*1024
    uv4 wrh[4], wrl[4];
#pragma unroll
    for (int i = 0; i < 4; ++i) {
        wrh[i] = w1src[i * 256 + tid];
        wrl[i] = w1src[4096 + i * 256 + tid];
    }
#pragma unroll
    for (int i = 0; i < 4; ++i) {
        int row = i * 16 + rbase;
        zt[row * 16 + (gz ^ (row & 15))] = zr[i];
    }

    // phase 1: acc1[mc][nr] = (W1hi+W1lo)^T-tile x z-tile
    fv4 acc1[4][4];
#pragma unroll
    for (int mc = 0; mc < 4; ++mc)
#pragma unroll
        for (int nr = 0; nr < 4; ++nr) acc1[mc][nr] = (fv4){0.f, 0.f, 0.f, 0.f};

    for (int kc = 0; kc < 4; ++kc) {
        __syncthreads();
#pragma unroll
        for (int i = 0; i < 4; ++i) {
            int g = i * 256 + tid;
            int wn = g >> 2, gw = g & 3;
            int slot = wn * 4 + (gw ^ ((wn >> 1) & 3));
            wt[slot] = wrh[i];
            wt[1024 + slot] = wrl[i];
        }
        __syncthreads();
        if (kc < 3) {
#pragma unroll
            for (int i = 0; i < 4; ++i) {
                wrh[i] = w1src[(size_t)(kc + 1) * 1024 + i * 256 + tid];
                wrl[i] = w1src[4096 + (size_t)(kc + 1) * 1024 + i * 256 + tid];
            }
        }
        bfv8 wfh[4], wfl[4], zf[4];
#pragma unroll
        for (int mc = 0; mc < 4; ++mc) {
            int col = wave * 64 + mc * 16 + lr;
            int slot = col * 4 + (lq ^ ((col >> 1) & 3));
            wfh[mc] = __builtin_bit_cast(bfv8, wt[slot]);
            wfl[mc] = __builtin_bit_cast(bfv8, wt[1024 + slot]);
        }
#pragma unroll
        for (int nr = 0; nr < 4; ++nr) {
            int row = nr * 16 + lr;
            zf[nr] = __builtin_bit_cast(bfv8, zt[row * 16 + ((kc * 4 + lq) ^ (row & 15))]);
        }
#pragma unroll
        for (int mc = 0; mc < 4; ++mc)
#pragma unroll
            for (int nr = 0; nr < 4; ++nr) {
                acc1[mc][nr] = __builtin_amdgcn_mfma_f32_16x16x32_bf16(wfh[mc], zf[nr], acc1[mc][nr], 0, 0, 0);
                acc1[mc][nr] = __builtin_amdgcn_mfma_f32_16x16x32_bf16(wfl[mc], zf[nr], acc1[mc][nr], 0, 0, 0);
            }
    }
    __syncthreads();

    const uv4* w2src = (const uv4*)W2l;      // hi chunks at kc*512, lo at 4096+kc*512
    uv4 wr2h[2], wr2l[2];
    wr2h[0] = w2src[tid]; wr2h[1] = w2src[256 + tid];
    wr2l[0] = w2src[4096 + tid]; wr2l[1] = w2src[4096 + 256 + tid];

    // epilogue1: bn1-apply + relu + bf16 pack -> at tile
#pragma unroll
    for (int mc = 0; mc < 4; ++mc) {
        int ycol0 = wave * 64 + mc * 16 + lq * 4;
        float4 s4 = *(const float4*)(sc1 + ycol0);
        float4 h4 = *(const float4*)(sh1 + ycol0);
        int gg = wave * 8 + mc * 2 + (lq >> 1);
#pragma unroll
        for (int nr = 0; nr < 4; ++nr) {
            int zrow = nr * 16 + lr;
            float v0 = fmaxf(acc1[mc][nr][0] * s4.x + h4.x, 0.f);
            float v1 = fmaxf(acc1[mc][nr][1] * s4.y + h4.y, 0.f);
            float v2 = fmaxf(acc1[mc][nr][2] * s4.z + h4.z, 0.f);
            float v3 = fmaxf(acc1[mc][nr][3] * s4.w + h4.w, 0.f);
            uint2 pk;
            pk.x = (unsigned int)f2bf(v0) | ((unsigned int)f2bf(v1) << 16);
            pk.y = (unsigned int)f2bf(v2) | ((unsigned int)f2bf(v3) << 16);
            int gs = gg ^ (zrow & 15);
            ((uint2*)at)[(zrow * 32 + gs) * 2 + (lq & 1)] = pk;
        }
    }

    // phase 2: y2 = at @ (W2hi+W2lo)
    fv4 acc2[4][2];
#pragma unroll
    for (int m = 0; m < 4; ++m) { acc2[m][0] = (fv4){0.f,0.f,0.f,0.f}; acc2[m][1] = (fv4){0.f,0.f,0.f,0.f}; }

    for (int kc = 0; kc < 8; ++kc) {
        __syncthreads();
        {
            int wn = tid >> 2, gw = tid & 3;
            int slot = wn * 4 + (gw ^ ((wn >> 1) & 3));
            wt2[slot] = wr2h[0];
            wt2[512 + slot] = wr2l[0];
            int g3 = 256 + tid, wn3 = g3 >> 2, gw3 = g3 & 3;
            int slot3 = wn3 * 4 + (gw3 ^ ((wn3 >> 1) & 3));
            wt2[slot3] = wr2h[1];
            wt2[512 + slot3] = wr2l[1];
        }
        __syncthreads();
        if (kc < 7) {
            wr2h[0] = w2src[(size_t)(kc + 1) * 512 + tid];
            wr2h[1] = w2src[(size_t)(kc + 1) * 512 + 256 + tid];
            wr2l[0] = w2src[4096 + (size_t)(kc + 1) * 512 + tid];
            wr2l[1] = w2src[4096 + (size_t)(kc + 1) * 512 + 256 + tid];
        }
        bfv8 a[4], bh[2], bl[2];
#pragma unroll
        for (int m = 0; m < 4; ++m) {
            int row = m * 16 + lr;
            a[m] = __builtin_bit_cast(bfv8, at[row * 32 + ((kc * 4 + lq) ^ (row & 15))]);
        }
#pragma unroll
        for (int nb = 0; nb < 2; ++nb) {
            int col = wave * 32 + nb * 16 + lr;
            int slot = col * 4 + (lq ^ ((col >> 1) & 3));
            bh[nb] = __builtin_bit_cast(bfv8, wt2[slot]);
            bl[nb] = __builtin_bit_cast(bfv8, wt2[512 + slot]);
        }
#pragma unroll
        for (int m = 0; m < 4; ++m)
#pragma unroll
            for (int nb = 0; nb < 2; ++nb) {
                acc2[m][nb] = __builtin_amdgcn_mfma_f32_16x16x32_bf16(a[m], bh[nb], acc2[m][nb], 0, 0, 0);
                acc2[m][nb] = __builtin_amdgcn_mfma_f32_16x16x32_bf16(a[m], bl[nb], acc2[m][nb], 0, 0, 0);
            }
    }

    float bv[2], s[2], q[2];
#pragma unroll
    for (int nb = 0; nb < 2; ++nb) {
        bv[nb] = bias2[wave * 32 + nb * 16 + lr];
        s[nb] = 0.f; q[nb] = 0.f;
    }
#pragma unroll
    for (int m = 0; m < 4; ++m)
#pragma unroll
        for (int nb = 0; nb < 2; ++nb) {
            int col = wave * 32 + nb * 16 + lr;
#pragma unroll
            for (int r = 0; r < 4; ++r) {
                float v = acc2[m][nb][r] + bv[nb];
                unsigned short ub = f2bf(v);
                float vr = bf2f(ub);
                int row = row0 + m * 16 + lq * 4 + r;
                y2h[(size_t)row * DD + col] = ub;
                s[nb] += vr; q[nb] += vr * vr;
            }
        }
#pragma unroll
    for (int nb = 0; nb < 2; ++nb) {
        s[nb] += __shfl_xor(s[nb], 16); s[nb] += __shfl_xor(s[nb], 32);
        q[nb] += __shfl_xor(q[nb], 16); q[nb] += __shfl_xor(q[nb], 32);
    }
    if (lane < 16) {
        int shb = (blockIdx.x & (NSHARD - 1)) * 256;
#pragma unroll
        for (int nb = 0; nb < 2; ++nb) {
            int col = wave * 32 + nb * 16 + lr;
            atomicAdd(shard + shb + col, s[nb]);
            atomicAdd(shard + shb + 128 + col, q[nb]);
        }
    }
}

// ---------- final: out = relu(bn2(y2h)) -> f32 ----------
__global__ __launch_bounds__(256) void k_bnfinal(const unsigned short* __restrict__ y2h,
        const float* __restrict__ sc2, const float* __restrict__ sh2,
        float* __restrict__ out, int N) {
    size_t base = ((size_t)blockIdx.x * 256 + threadIdx.x) * 4;
    if (base >= (size_t)N * DD) return;
    int c = (int)(base & (DD - 1));
    ushort4 v = *(const ushort4*)(y2h + base);
    float4 s = *(const float4*)(sc2 + c);
    float4 t = *(const float4*)(sh2 + c);
    float4 o;
    o.x = fmaxf(bf2f(v.x) * s.x + t.x, 0.f);
    o.y = fmaxf(bf2f(v.y) * s.y + t.y, 0.f);
    o.z = fmaxf(bf2f(v.z) * s.z + t.z, 0.f);
    o.w = fmaxf(bf2f(v.w) * s.w + t.w, 0.f);
    *(float4*)(out + base) = o;
}

extern "C" void kernel_launch(void* const* d_in, const int* in_sizes, int n_in,
                              void* d_out, int out_size, void* d_ws, size_t ws_size,
                              hipStream_t stream) {
    const int* x = (const int*)d_in[0];
    const int* ei = (const int*)d_in[1];
    const int* ea = (const int*)d_in[2];
    const float* atom_emb = (const float*)d_in[3];
    const float* bond_emb = (const float*)d_in[4];
    const float* W1 = (const float*)d_in[5];
    const float* b1 = (const float*)d_in[6];
    const float* bn1_g = (const float*)d_in[7];
    const float* bn1_b = (const float*)d_in[8];
    const float* W2 = (const float*)d_in[9];
    const float* b2 = (const float*)d_in[10];
    const float* epsv = (const float*)d_in[11];
    const float* obn_g = (const float*)d_in[12];
    const float* obn_b = (const float*)d_in[13];
    int N = in_sizes[0] / NF_ATOM;   // 200000 (divisible by 64)
    int E = in_sizes[1] / 2;

    char* wsb = (char*)d_ws;
    unsigned short* y2h = (unsigned short*)wsb;                        // N*128 bf16
    unsigned short* zb = (unsigned short*)(wsb + (size_t)N * 256);     // N*128 bf16
    int* epack = (int*)(wsb + (size_t)N * 512);                        // E int
    unsigned short* w1t = (unsigned short*)(wsb + (size_t)N * 512 + (size_t)E * 4);  // 5*65536
    unsigned short* w2t = w1t + 327680;                                // 5*65536
    float* btab = (float*)((char*)w2t + 655360);                       // 5*216*128 f32
    float* sc1 = btab + NLAYER * NCODE * DD;                           // 256
    float* sh1 = sc1 + 256;
    float* sc2 = sh1 + 256;                                            // 128
    float* sh2 = sc2 + 128;
    float* G = sh2 + 128;                                              // 16384
    float* cs = G + DD * DD;                                           // 128
    float* shardG = cs + DD;                                           // 256*16384 (reused per layer)
    float* csS = shardG + (size_t)GRAM_NB * DD * DD;                   // 256*128
    float* shard2 = csS + GRAM_NB * DD;                                // 5 * 32*256 (zeroed)
    size_t zero_f = (size_t)NLAYER * NSHARD * 256;
    int* rsarr = (int*)(shard2 + (size_t)NLAYER * NSHARD * 256);       // N+1
    int* bsum = rsarr + (N + 1);
    int* boff = bsum + 256;
    float invN = 1.0f / (float)N;
    int nbk = (N + 1023) / 1024;

    k_wconv<<<1280, 256, 0, stream>>>(W1, W2, w1t, w2t);
    k_bsumtab<<<(NLAYER * NCODE * DD + 255) / 256, 256, 0, stream>>>(bond_emb, btab);
    hipMemsetAsync(rsarr, 0, ((size_t)N + 1) * 4, stream);
    hipMemsetAsync(shard2, 0, zero_f * sizeof(float), stream);
    k_deg<<<(E + 255) / 256, 256, 0, stream>>>(ei, rsarr, E);
    k_bsum<<<nbk, 256, 0, stream>>>(rsarr, bsum, N);
    k_bscan<<<1, 256, 0, stream>>>(bsum, boff, nbk);
    k_csr<<<nbk, 256, 0, stream>>>(rsarr, boff, rsarr, N, E);
    k_scatter<<<(E + 255) / 256, 256, 0, stream>>>(ei, ea, rsarr, epack, E);
    k_atom<<<(N * 32 + 255) / 256, 256, 0, stream>>>(x, atom_emb, y2h, N);

    int gb = N / 64;
    for (int l = 0; l < NLAYER; ++l) {
        float* sh2d = shard2 + (size_t)l * NSHARD * 256;
        k_zbuild<<<(N * 32 + 255) / 256, 256, 0, stream>>>(y2h, rsarr, epack,
                btab + (size_t)l * NCODE * DD, sc2, sh2, epsv, l, (l == 0) ? 0 : 1, zb, N);
        k_gram<<<GRAM_NB, 256, 0, stream>>>(zb, shardG, csS, N);
        k_gred<<<(DD * DD + DD + 255) / 256, 256, 0, stream>>>(shardG, csS, G, cs);
        k_redG<<<HH, 128, 0, stream>>>(G, cs, w1t + (size_t)l * 65536, b1 + l * HH,
                bn1_g + l * HH, bn1_b + l * HH, invN, sc1, sh1);
        k_fgemm<<<gb, 256, 0, stream>>>(zb, w1t + (size_t)l * 65536, w2t + (size_t)l * 65536,
                sc1, sh1, b2 + l * DD, y2h, sh2d, N);
        k_red<<<1, 128, 0, stream>>>(sh2d, 128, obn_g + l * DD, obn_b + l * DD, invN, sc2, sh2);
    }
    k_bnfinal<<<(int)(((size_t)N * DD / 4 + 255) / 256), 256, 0, stream>>>(
            y2h, sc2, sh2, (float*)d_out, N);
}

// Round 15
// 904.273 us; speedup vs baseline: 1.2224x; 1.0275x over previous
//
#include <hip/hip_runtime.h>

#define NF_ATOM 9
#define NF_BOND 3
#define DD 128
#define HH 256
#define NLAYER 5
#define NSHARD 32
#define NCODE 216
#define GRAM_NB 256

typedef float fv4 __attribute__((ext_vector_type(4)));
typedef __bf16 bfv8 __attribute__((ext_vector_type(8)));
typedef unsigned int uv4 __attribute__((ext_vector_type(4)));

__device__ inline unsigned short f2bf(float f) {
    unsigned int u = __builtin_bit_cast(unsigned int, f);
    u = u + 0x7FFFu + ((u >> 16) & 1u);
    return (unsigned short)(u >> 16);
}
__device__ inline float bf2f(unsigned short s) {
    unsigned int u = ((unsigned int)s) << 16;
    return __builtin_bit_cast(float, u);
}

// ---------- atom encoder: h0 -> bf16 state ----------
__global__ __launch_bounds__(256) void k_atom(const int* __restrict__ x,
        const float* __restrict__ emb, unsigned short* __restrict__ h, int N) {
    int gid = blockIdx.x * 256 + threadIdx.x;
    int n = gid >> 5;
    if (n >= N) return;
    int c = (gid & 31) << 2;
    const int* xr = x + n * NF_ATOM;
    float4 acc = make_float4(0.f, 0.f, 0.f, 0.f);
#pragma unroll
    for (int f = 0; f < NF_ATOM; ++f) {
        int idx = xr[f];
        float4 v = *(const float4*)(emb + ((size_t)(f * 120 + idx) * DD) + c);
        acc.x += v.x; acc.y += v.y; acc.z += v.z; acc.w += v.w;
    }
    ushort4 o;
    o.x = f2bf(acc.x); o.y = f2bf(acc.y); o.z = f2bf(acc.z); o.w = f2bf(acc.w);
    *(ushort4*)(h + (size_t)n * DD + c) = o;
}

// ---------- weight convert: split bf16 (hi + residual lo), chunk-major ----------
__global__ __launch_bounds__(256) void k_wconv(const float* __restrict__ W1,
        const float* __restrict__ W2, unsigned short* __restrict__ W1t,
        unsigned short* __restrict__ W2t) {
    int id = blockIdx.x * 256 + threadIdx.x;
    const int T1 = NLAYER * 4 * 256 * 32;      // 163840
    if (id < T1) {
        int k = id & 31, n = (id >> 5) & 255, kc = (id >> 13) & 3, l = id >> 15;
        int o = id & 32767;
        float w = W1[((size_t)(l * 128 + kc * 32 + k)) * 256 + n];
        unsigned short hi = f2bf(w);
        W1t[(size_t)l * 65536 + o] = hi;
        W1t[(size_t)l * 65536 + 32768 + o] = f2bf(w - bf2f(hi));
    } else {
        int id2 = id - T1;
        if (id2 >= NLAYER * 8 * 128 * 32) return;
        int k = id2 & 31, n = (id2 >> 5) & 127, kc = (id2 >> 12) & 7, l = id2 >> 15;
        int o = id2 & 32767;
        float w = W2[((size_t)(l * 256 + kc * 32 + k)) * 128 + n];
        unsigned short hi = f2bf(w);
        W2t[(size_t)l * 65536 + o] = hi;
        W2t[(size_t)l * 65536 + 32768 + o] = f2bf(w - bf2f(hi));
    }
}

// ---------- bond-sum table ----------
__global__ __launch_bounds__(256) void k_bsumtab(const float* __restrict__ bemb,
        float* __restrict__ tab) {
    int id = blockIdx.x * 256 + threadIdx.x;
    if (id >= NLAYER * NCODE * DD) return;
    int c = id & 127;
    int code = (id >> 7) % NCODE;
    int l = id / (NCODE * DD);
    int a0 = code % 6, a1 = (code / 6) % 6, a2 = code / 36;
    const float* bl = bemb + (size_t)l * NF_BOND * 6 * DD;
    tab[id] = bl[(0 * 6 + a0) * DD + c] + bl[(1 * 6 + a1) * DD + c] + bl[(2 * 6 + a2) * DD + c];
}

// ---------- CSR build ----------
__global__ __launch_bounds__(256) void k_deg(const int* __restrict__ ei, int* __restrict__ deg, int E) {
    int e = blockIdx.x * 256 + threadIdx.x;
    if (e < E) atomicAdd(&deg[ei[E + e]], 1);
}
__global__ __launch_bounds__(256) void k_bsum(const int* __restrict__ deg, int* __restrict__ bsum, int N) {
    __shared__ int red[256];
    int t = threadIdx.x, b = blockIdx.x;
    int i0 = b * 1024 + t * 4;
    int s = 0;
#pragma unroll
    for (int j = 0; j < 4; ++j) if (i0 + j < N) s += deg[i0 + j];
    red[t] = s; __syncthreads();
    for (int off = 128; off > 0; off >>= 1) {
        if (t < off) red[t] += red[t + off];
        __syncthreads();
    }
    if (t == 0) bsum[b] = red[0];
}
__global__ __launch_bounds__(256) void k_bscan(const int* __restrict__ bsum, int* __restrict__ boff, int nb) {
    __shared__ int ts[256];
    int t = threadIdx.x;
    int v = (t < nb) ? bsum[t] : 0;
    ts[t] = v; __syncthreads();
    for (int off = 1; off < 256; off <<= 1) {
        int u = (t >= off) ? ts[t - off] : 0;
        __syncthreads();
        ts[t] += u;
        __syncthreads();
    }
    if (t < nb) boff[t] = ts[t] - v;   // exclusive
}
__global__ __launch_bounds__(256) void k_csr(const int* deg, const int* __restrict__ boff,
        int* rs, int N, int E) {
    __shared__ int ts[256];
    int t = threadIdx.x, b = blockIdx.x;
    int i0 = b * 1024 + t * 4;
    int d[4];
#pragma unroll
    for (int j = 0; j < 4; ++j) d[j] = (i0 + j < N) ? deg[i0 + j] : 0;
    int tsum = d[0] + d[1] + d[2] + d[3];
    ts[t] = tsum; __syncthreads();
    for (int off = 1; off < 256; off <<= 1) {
        int u = (t >= off) ? ts[t - off] : 0;
        __syncthreads();
        ts[t] += u;
        __syncthreads();
    }
    int base = boff[b] + ts[t] - tsum;
    int p = 0;
#pragma unroll
    for (int j = 0; j < 4; ++j) {
        int dj = d[j];
        if (i0 + j < N) rs[i0 + j] = base + p;
        p += dj;
    }
    if (b == 0 && t == 0) rs[N] = E;
}
// packed record: src (18 bits) | code6 << 18
__global__ __launch_bounds__(256) void k_scatter(const int* __restrict__ ei,
        const int* __restrict__ ea, int* __restrict__ rs, int* __restrict__ epack, int E) {
    int e = blockIdx.x * 256 + threadIdx.x;
    if (e < E) {
        int pos = atomicAdd(&rs[ei[E + e]], 1);
        int code = ea[e * 3 + 0] + 6 * ea[e * 3 + 1] + 36 * ea[e * 3 + 2];
        epack[pos] = ei[e] | (code << 18);
    }
}

// ---------- BN2 shard reduce -> scale/shift ----------
__global__ void k_red(const float* __restrict__ sh, int C, const float* __restrict__ bng,
        const float* __restrict__ bnb, float invN,
        float* __restrict__ sc_out, float* __restrict__ sh_out) {
    int t = threadIdx.x;
    if (t >= C) return;
    float a = 0.f, qq = 0.f;
#pragma unroll
    for (int s = 0; s < NSHARD; ++s) {
        a += sh[s * 2 * C + t];
        qq += sh[s * 2 * C + C + t];
    }
    float mu = a * invN;
    float var = qq * invN - mu * mu;
    float r = rsqrtf(var + 1e-5f);
    float sc = bng[t] * r;
    sc_out[t] = sc; sh_out[t] = bnb[t] - mu * sc;
}

// ---------- zbuild ----------
__device__ inline void edge_acc(ushort4 hv, float4 bv, float4 sc, float4 sh, int mode, float* ag) {
    float h0 = bf2f(hv.x), h1 = bf2f(hv.y), h2 = bf2f(hv.z), h3 = bf2f(hv.w);
    if (mode) {
        h0 = fmaxf(h0 * sc.x + sh.x, 0.f); h1 = fmaxf(h1 * sc.y + sh.y, 0.f);
        h2 = fmaxf(h2 * sc.z + sh.z, 0.f); h3 = fmaxf(h3 * sc.w + sh.w, 0.f);
    }
    ag[0] += fmaxf(h0 + bv.x, 0.f); ag[1] += fmaxf(h1 + bv.y, 0.f);
    ag[2] += fmaxf(h2 + bv.z, 0.f); ag[3] += fmaxf(h3 + bv.w, 0.f);
}

__global__ __launch_bounds__(256) void k_zbuild(const unsigned short* __restrict__ y2h,
        const int* __restrict__ rs, const int* __restrict__ epack,
        const float* __restrict__ btab, const float* __restrict__ sctab,
        const float* __restrict__ shtab, const float* __restrict__ epsv,
        int l, int mode, unsigned short* __restrict__ z, int N) {
    int gid = blockIdx.x * 256 + threadIdx.x;
    int n = gid >> 5;
    if (n >= N) return;
    int c = (gid & 31) << 2;
    float4 sc4 = make_float4(1.f, 1.f, 1.f, 1.f), sh4 = make_float4(0.f, 0.f, 0.f, 0.f);
    if (mode) { sc4 = *(const float4*)(sctab + c); sh4 = *(const float4*)(shtab + c); }
    int p0 = (n == 0) ? 0 : rs[n - 1];
    int p1 = rs[n];
    float ag[4] = {0.f, 0.f, 0.f, 0.f};
    int p = p0;
    for (; p + 2 <= p1; p += 2) {
        int rec0 = epack[p], rec1 = epack[p + 1];
        int s0 = rec0 & 0x3FFFF, s1 = rec1 & 0x3FFFF;
        int c0 = ((unsigned int)rec0) >> 18, c1 = ((unsigned int)rec1) >> 18;
        ushort4 h0 = *(const ushort4*)(y2h + (size_t)s0 * DD + c);
        ushort4 h1 = *(const ushort4*)(y2h + (size_t)s1 * DD + c);
        float4 b0 = *(const float4*)(btab + (size_t)c0 * DD + c);
        float4 b1 = *(const float4*)(btab + (size_t)c1 * DD + c);
        edge_acc(h0, b0, sc4, sh4, mode, ag);
        edge_acc(h1, b1, sc4, sh4, mode, ag);
    }
    if (p < p1) {
        int rec = epack[p];
        int s0 = rec & 0x3FFFF;
        int c0 = ((unsigned int)rec) >> 18;
        ushort4 h0 = *(const ushort4*)(y2h + (size_t)s0 * DD + c);
        float4 b0 = *(const float4*)(btab + (size_t)c0 * DD + c);
        edge_acc(h0, b0, sc4, sh4, mode, ag);
    }
    float ep = 1.0f + epsv[l];
    ushort4 sv = *(const ushort4*)(y2h + (size_t)n * DD + c);
    float hz[4] = {bf2f(sv.x), bf2f(sv.y), bf2f(sv.z), bf2f(sv.w)};
    if (mode) {
        hz[0] = fmaxf(hz[0] * sc4.x + sh4.x, 0.f);
        hz[1] = fmaxf(hz[1] * sc4.y + sh4.y, 0.f);
        hz[2] = fmaxf(hz[2] * sc4.z + sh4.z, 0.f);
        hz[3] = fmaxf(hz[3] * sc4.w + sh4.w, 0.f);
    }
    ushort4 o;
    o.x = f2bf(ep * hz[0] + ag[0]);
    o.y = f2bf(ep * hz[1] + ag[1]);
    o.z = f2bf(ep * hz[2] + ag[2]);
    o.w = f2bf(ep * hz[3] + ag[3]);
    *(ushort4*)(z + (size_t)n * DD + c) = o;
}

// ---------- Gram: per-block partial G = Z^T Z + colsum, direct stores (no atomics) ----------
__global__ __launch_bounds__(256) void k_gram(const unsigned short* __restrict__ z,
        float* __restrict__ shardG, float* __restrict__ csS, int N) {
    __shared__ uv4 zT[128 * 8];   // transposed tile [ch][8 granules of 8 rows], 16KB
    int tid = threadIdx.x;
    int lane = tid & 63, wave = tid >> 6, lq = lane >> 4, lr = lane & 15;
    int cg = tid & 15;
    float cs[8] = {0, 0, 0, 0, 0, 0, 0, 0};
    fv4 acc[2][8];
#pragma unroll
    for (int ti = 0; ti < 2; ++ti)
#pragma unroll
        for (int tj = 0; tj < 8; ++tj) acc[ti][tj] = (fv4){0.f, 0.f, 0.f, 0.f};

    int ntile = N >> 6;
    for (int t = blockIdx.x; t < ntile; t += GRAM_NB) {
        const unsigned short* zt0 = z + ((size_t)t << 6) * DD;
        __syncthreads();
#pragma unroll
        for (int i = 0; i < 2; ++i) {
            int rp = i * 16 + (tid >> 4);
            int r0 = rp * 2;
            uv4 a = *(const uv4*)(zt0 + (size_t)r0 * DD + cg * 8);
            uv4 b = *(const uv4*)(zt0 + (size_t)(r0 + 1) * DD + cg * 8);
            int g = rp >> 2;
            int eo = rp & 3;
#pragma unroll
            for (int j = 0; j < 4; ++j) {
                unsigned int lo0 = a[j] & 0xFFFFu, hi0 = a[j] >> 16;
                unsigned int lo1 = b[j] & 0xFFFFu, hi1 = b[j] >> 16;
                cs[2 * j] += bf2f((unsigned short)lo0) + bf2f((unsigned short)lo1);
                cs[2 * j + 1] += bf2f((unsigned short)hi0) + bf2f((unsigned short)hi1);
                int ch0 = cg * 8 + 2 * j, ch1 = ch0 + 1;
                int s0 = ch0 * 8 + (g ^ ((ch0 ^ (ch0 >> 3)) & 7));
                int s1 = ch1 * 8 + (g ^ ((ch1 ^ (ch1 >> 3)) & 7));
                ((unsigned int*)zT)[s0 * 4 + eo] = lo0 | (lo1 << 16);
                ((unsigned int*)zT)[s1 * 4 + eo] = hi0 | (hi1 << 16);
            }
        }
        __syncthreads();
#pragma unroll
        for (int ks = 0; ks < 2; ++ks) {
            bfv8 af[2], bfr[8];
#pragma unroll
            for (int ti = 0; ti < 2; ++ti) {
                int ch = wave * 32 + ti * 16 + lr;
                af[ti] = __builtin_bit_cast(bfv8, zT[ch * 8 + ((ks * 4 + lq) ^ ((ch ^ (ch >> 3)) & 7))]);
            }
#pragma unroll
            for (int tj = 0; tj < 8; ++tj) {
                int ch = tj * 16 + lr;
                bfr[tj] = __builtin_bit_cast(bfv8, zT[ch * 8 + ((ks * 4 + lq) ^ ((ch ^ (ch >> 3)) & 7))]);
            }
#pragma unroll
            for (int ti = 0; ti < 2; ++ti)
#pragma unroll
                for (int tj = 0; tj < 8; ++tj)
                    acc[ti][tj] = __builtin_amdgcn_mfma_f32_16x16x32_bf16(af[ti], bfr[tj], acc[ti][tj], 0, 0, 0);
        }
    }
    float* gsh = shardG + (size_t)blockIdx.x * (DD * DD);
#pragma unroll
    for (int ti = 0; ti < 2; ++ti) {
        int gi = wave * 32 + ti * 16 + lq * 4;
#pragma unroll
        for (int tj = 0; tj < 8; ++tj) {
            int gj = tj * 16 + lr;
#pragma unroll
            for (int r = 0; r < 4; ++r)
                gsh[(size_t)(gi + r) * DD + gj] = acc[ti][tj][r];
        }
    }
    __syncthreads();
    float* red = (float*)zT;
#pragma unroll
    for (int j = 0; j < 8; ++j) red[tid * 8 + j] = cs[j];
    __syncthreads();
    if (tid < 128) {
        int cgg = tid >> 3, j = tid & 7;
        float a = 0.f;
#pragma unroll
        for (int k = 0; k < 16; ++k) a += red[(k * 16 + cgg) * 8 + j];
        csS[blockIdx.x * DD + cgg * 8 + j] = a;
    }
}

// ---------- reduce G/cs shards to dense ----------
__global__ __launch_bounds__(256) void k_gred(const float* __restrict__ shardG,
        const float* __restrict__ csS, float* __restrict__ G, float* __restrict__ cs) {
    int idx = blockIdx.x * 256 + threadIdx.x;
    if (idx < DD * DD) {
        float a = 0.f;
#pragma unroll 8
        for (int s = 0; s < GRAM_NB; ++s) a += shardG[(size_t)s * DD * DD + idx];
        G[idx] = a;
    } else if (idx < DD * DD + DD) {
        int t = idx - DD * DD;
        float a = 0.f;
#pragma unroll 8
        for (int s = 0; s < GRAM_NB; ++s) a += csS[s * DD + t];
        cs[t] = a;
    }
}

// ---------- BN1 stats from Gram ----------
__global__ __launch_bounds__(128) void k_redG(const float* __restrict__ G,
        const float* __restrict__ cs, const unsigned short* __restrict__ W1l,
        const float* __restrict__ b1, const float* __restrict__ bng,
        const float* __restrict__ bnb, float invN,
        float* __restrict__ sc_out, float* __restrict__ sh_out) {
    __shared__ float wv[128];
    __shared__ float redA[128], redB[128];
    int j = blockIdx.x;
    int t = threadIdx.x;
    int kc = t >> 5, kk = t & 31;
    int o = kc * 8192 + j * 32 + kk;
    float w_t = bf2f(W1l[o]) + bf2f(W1l[32768 + o]);
    wv[t] = w_t;
    __syncthreads();
    const float4* Gr = (const float4*)(G + (size_t)t * DD);
    float d = 0.f;
#pragma unroll
    for (int i = 0; i < 32; ++i) {
        float4 g4 = Gr[i];
        d += g4.x * wv[i * 4] + g4.y * wv[i * 4 + 1] + g4.z * wv[i * 4 + 2] + g4.w * wv[i * 4 + 3];
    }
    redA[t] = w_t * d;
    redB[t] = cs[t] * w_t;
    __syncthreads();
    for (int off = 64; off > 0; off >>= 1) {
        if (t < off) { redA[t] += redA[t + off]; redB[t] += redB[t + off]; }
        __syncthreads();
    }
    if (t == 0) {
        float bj = b1[j];
        float csw = redB[0];
        float mean = csw * invN + bj;
        float ey2 = redA[0] * invN + 2.f * bj * csw * invN + bj * bj;
        float var = ey2 - mean * mean;
        float r = rsqrtf(var + 1e-5f);
        float sc = bng[j] * r;
        sc_out[j] = sc;
        sh_out[j] = bnb[j] - mean * sc + bj * sc;
    }
}

// ---------- fused GEMM, wave-private weight staging (3 barriers total) ----------
// LDS map: phase1: zt=smem[0..1024), wtH=[1024..2048) (wave*256), wtL=[2048..3072)
//          phase2: at=smem[0..2048), wt2H=[2048..2560) (wave*128), wt2L=[2560..3072)
__global__ __launch_bounds__(256) void k_fgemm(const unsigned short* __restrict__ z,
        const unsigned short* __restrict__ W1l, const unsigned short* __restrict__ W2l,
        const float* __restrict__ sc1, const float* __restrict__ sh1,
        const float* __restrict__ bias2,
        unsigned short* __restrict__ y2h, float* __restrict__ shard, int N) {
    __shared__ uv4 smem[3072];           // 48KB
    uv4* zt = smem;
    uv4* wtH = smem + 1024;
    uv4* wtL = smem + 2048;
    uv4* at = smem;
    uv4* wt2H = smem + 2048;
    uv4* wt2L = smem + 2560;
    int tid = threadIdx.x;
    int row0 = blockIdx.x * 64;
    int wave = tid >> 6, lane = tid & 63, lq = lane >> 4, lr = lane & 15;
    int rbase = tid >> 4, gz = tid & 15;

    // stage z tile (shared) + W1 kc0 (wave-private)
    uv4 zr[4];
#pragma unroll
    for (int i = 0; i < 4; ++i)
        zr[i] = *(const uv4*)(z + (size_t)(row0 + i * 16 + rbase) * DD + gz * 8);
    const uv4* w1src = (const uv4*)W1l;      // hi at kc*1024, lo at 4096+kc*1024
    uv4 wrh[4], wrl[4];
#pragma unroll
    for (int i = 0; i < 4; ++i) {
        int gloc = i * 64 + lane;            // 0..255 within wave slice
        wrh[i] = w1src[wave * 256 + gloc];
        wrl[i] = w1src[4096 + wave * 256 + gloc];
    }
#pragma unroll
    for (int i = 0; i < 4; ++i) {
        int row = i * 16 + rbase;
        zt[row * 16 + (gz ^ (row & 15))] = zr[i];
    }
#pragma unroll
    for (int i = 0; i < 4; ++i) {
        int gloc = i * 64 + lane;
        int lc = gloc >> 2, gw = gloc & 3;
        int slot = wave * 256 + lc * 4 + (gw ^ ((lc >> 1) & 3));
        wtH[slot] = wrh[i];
        wtL[slot] = wrl[i];
    }
    __syncthreads();   // barrier 1/3: zt visible to all waves

    fv4 acc1[4][4];
#pragma unroll
    for (int mc = 0; mc < 4; ++mc)
#pragma unroll
        for (int nr = 0; nr < 4; ++nr) acc1[mc][nr] = (fv4){0.f, 0.f, 0.f, 0.f};

    for (int kc = 0; kc < 4; ++kc) {
        if (kc < 3) {
#pragma unroll
            for (int i = 0; i < 4; ++i) {
                int gloc = i * 64 + lane;
                wrh[i] = w1src[(size_t)(kc + 1) * 1024 + wave * 256 + gloc];
                wrl[i] = w1src[4096 + (size_t)(kc + 1) * 1024 + wave * 256 + gloc];
            }
        }
        bfv8 wfh[4], wfl[4], zf[4];
#pragma unroll
        for (int mc = 0; mc < 4; ++mc) {
            int lc = mc * 16 + lr;
            int slot = wave * 256 + lc * 4 + (lq ^ ((lc >> 1) & 3));
            wfh[mc] = __builtin_bit_cast(bfv8, wtH[slot]);
            wfl[mc] = __builtin_bit_cast(bfv8, wtL[slot]);
        }
#pragma unroll
        for (int nr = 0; nr < 4; ++nr) {
            int row = nr * 16 + lr;
            zf[nr] = __builtin_bit_cast(bfv8, zt[row * 16 + ((kc * 4 + lq) ^ (row & 15))]);
        }
#pragma unroll
        for (int mc = 0; mc < 4; ++mc)
#pragma unroll
            for (int nr = 0; nr < 4; ++nr) {
                acc1[mc][nr] = __builtin_amdgcn_mfma_f32_16x16x32_bf16(wfh[mc], zf[nr], acc1[mc][nr], 0, 0, 0);
                acc1[mc][nr] = __builtin_amdgcn_mfma_f32_16x16x32_bf16(wfl[mc], zf[nr], acc1[mc][nr], 0, 0, 0);
            }
        asm volatile("" ::: "memory");   // pin: this kc's LDS reads before next writes
        if (kc < 3) {
#pragma unroll
            for (int i = 0; i < 4; ++i) {
                int gloc = i * 64 + lane;
                int lc = gloc >> 2, gw = gloc & 3;
                int slot = wave * 256 + lc * 4 + (gw ^ ((lc >> 1) & 3));
                wtH[slot] = wrh[i];
                wtL[slot] = wrl[i];
            }
        }
    }
    __syncthreads();   // barrier 2/3: all waves done reading zt/wt before at-writes

    const uv4* w2src = (const uv4*)W2l;      // hi at kc*512, lo at 4096+kc*512
    uv4 wr2h[2], wr2l[2];
#pragma unroll
    for (int i = 0; i < 2; ++i) {
        int gloc = i * 64 + lane;            // 0..127 within wave slice
        wr2h[i] = w2src[wave * 128 + gloc];
        wr2l[i] = w2src[4096 + wave * 128 + gloc];
    }

    // epilogue1: bn1-apply + relu + bf16 pack -> at tile; stage W2 kc0 (wave-private)
#pragma unroll
    for (int mc = 0; mc < 4; ++mc) {
        int ycol0 = wave * 64 + mc * 16 + lq * 4;
        float4 s4 = *(const float4*)(sc1 + ycol0);
        float4 h4 = *(const float4*)(sh1 + ycol0);
        int gg = wave * 8 + mc * 2 + (lq >> 1);
#pragma unroll
        for (int nr = 0; nr < 4; ++nr) {
            int zrow = nr * 16 + lr;
            float v0 = fmaxf(acc1[mc][nr][0] * s4.x + h4.x, 0.f);
            float v1 = fmaxf(acc1[mc][nr][1] * s4.y + h4.y, 0.f);
            float v2 = fmaxf(acc1[mc][nr][2] * s4.z + h4.z, 0.f);
            float v3 = fmaxf(acc1[mc][nr][3] * s4.w + h4.w, 0.f);
            uint2 pk;
            pk.x = (unsigned int)f2bf(v0) | ((unsigned int)f2bf(v1) << 16);
            pk.y = (unsigned int)f2bf(v2) | ((unsigned int)f2bf(v3) << 16);
            int gs = gg ^ (zrow & 15);
            ((uint2*)at)[(zrow * 32 + gs) * 2 + (lq & 1)] = pk;
        }
    }
#pragma unroll
    for (int i = 0; i < 2; ++i) {
        int gloc = i * 64 + lane;
        int lc = gloc >> 2, gw = gloc & 3;
        int slot = wave * 128 + lc * 4 + (gw ^ ((lc >> 1) & 3));
        wt2H[slot] = wr2h[i];
        wt2L[slot] = wr2l[i];
    }
    __syncthreads();   // barrier 3/3: at visible to all waves

    fv4 acc2[4][2];
#pragma unroll
    for (int m = 0; m < 4; ++m) { acc2[m][0] = (fv4){0.f,0.f,0.f,0.f}; acc2[m][1] = (fv4){0.f,0.f,0.f,0.f}; }

    for (int kc = 0; kc < 8; ++kc) {
        if (kc < 7) {
#pragma unroll
            for (int i = 0; i < 2; ++i) {
                int gloc = i * 64 + lane;
                wr2h[i] = w2src[(size_t)(kc + 1) * 512 + wave * 128 + gloc];
                wr2l[i] = w2src[4096 + (size_t)(kc + 1) * 512 + wave * 128 + gloc];
            }
        }
        bfv8 a[4], bh[2], bl[2];
#pragma unroll
        for (int m = 0; m < 4; ++m) {
            int row = m * 16 + lr;
            a[m] = __builtin_bit_cast(bfv8, at[row * 32 + ((kc * 4 + lq) ^ (row & 15))]);
        }
#pragma unroll
        for (int nb = 0; nb < 2; ++nb) {
            int lc = nb * 16 + lr;
            int slot = wave * 128 + lc * 4 + (lq ^ ((lc >> 1) & 3));
            bh[nb] = __builtin_bit_cast(bfv8, wt2H[slot]);
            bl[nb] = __builtin_bit_cast(bfv8, wt2L[slot]);
        }
#pragma unroll
        for (int m = 0; m < 4; ++m)
#pragma unroll
            for (int nb = 0; nb < 2; ++nb) {
                acc2[m][nb] = __builtin_amdgcn_mfma_f32_16x16x32_bf16(a[m], bh[nb], acc2[m][nb], 0, 0, 0);
                acc2[m][nb] = __builtin_amdgcn_mfma_f32_16x16x32_bf16(a[m], bl[nb], acc2[m][nb], 0, 0, 0);
            }
        asm volatile("" ::: "memory");
        if (kc < 7) {
#pragma unroll
            for (int i = 0; i < 2; ++i) {
                int gloc = i * 64 + lane;
                int lc = gloc >> 2, gw = gloc & 3;
                int slot = wave * 128 + lc * 4 + (gw ^ ((lc >> 1) & 3));
                wt2H[slot] = wr2h[i];
                wt2L[slot] = wr2l[i];
            }
        }
    }

    float bv[2], s[2], q[2];
#pragma unroll
    for (int nb = 0; nb < 2; ++nb) {
        bv[nb] = bias2[wave * 32 + nb * 16 + lr];
        s[nb] = 0.f; q[nb] = 0.f;
    }
#pragma unroll
    for (int m = 0; m < 4; ++m)
#pragma unroll
        for (int nb = 0; nb < 2; ++nb) {
            int col = wave * 32 + nb * 16 + lr;
#pragma unroll
            for (int r = 0; r < 4; ++r) {
                float v = acc2[m][nb][r] + bv[nb];
                unsigned short ub = f2bf(v);
                float vr = bf2f(ub);
                int row = row0 + m * 16 + lq * 4 + r;
                y2h[(size_t)row * DD + col] = ub;
                s[nb] += vr; q[nb] += vr * vr;
            }
        }
#pragma unroll
    for (int nb = 0; nb < 2; ++nb) {
        s[nb] += __shfl_xor(s[nb], 16); s[nb] += __shfl_xor(s[nb], 32);
        q[nb] += __shfl_xor(q[nb], 16); q[nb] += __shfl_xor(q[nb], 32);
    }
    if (lane < 16) {
        int shb = (blockIdx.x & (NSHARD - 1)) * 256;
#pragma unroll
        for (int nb = 0; nb < 2; ++nb) {
            int col = wave * 32 + nb * 16 + lr;
            atomicAdd(shard + shb + col, s[nb]);
            atomicAdd(shard + shb + 128 + col, q[nb]);
        }
    }
}

// ---------- final: out = relu(bn2(y2h)) -> f32 ----------
__global__ __launch_bounds__(256) void k_bnfinal(const unsigned short* __restrict__ y2h,
        const float* __restrict__ sc2, const float* __restrict__ sh2,
        float* __restrict__ out, int N) {
    size_t base = ((size_t)blockIdx.x * 256 + threadIdx.x) * 4;
    if (base >= (size_t)N * DD) return;
    int c = (int)(base & (DD - 1));
    ushort4 v = *(const ushort4*)(y2h + base);
    float4 s = *(const float4*)(sc2 + c);
    float4 t = *(const float4*)(sh2 + c);
    float4 o;
    o.x = fmaxf(bf2f(v.x) * s.x + t.x, 0.f);
    o.y = fmaxf(bf2f(v.y) * s.y + t.y, 0.f);
    o.z = fmaxf(bf2f(v.z) * s.z + t.z, 0.f);
    o.w = fmaxf(bf2f(v.w) * s.w + t.w, 0.f);
    *(float4*)(out + base) = o;
}

extern "C" void kernel_launch(void* const* d_in, const int* in_sizes, int n_in,
                              void* d_out, int out_size, void* d_ws, size_t ws_size,
                              hipStream_t stream) {
    const int* x = (const int*)d_in[0];
    const int* ei = (const int*)d_in[1];
    const int* ea = (const int*)d_in[2];
    const float* atom_emb = (const float*)d_in[3];
    const float* bond_emb = (const float*)d_in[4];
    const float* W1 = (const float*)d_in[5];
    const float* b1 = (const float*)d_in[6];
    const float* bn1_g = (const float*)d_in[7];
    const float* bn1_b = (const float*)d_in[8];
    const float* W2 = (const float*)d_in[9];
    const float* b2 = (const float*)d_in[10];
    const float* epsv = (const float*)d_in[11];
    const float* obn_g = (const float*)d_in[12];
    const float* obn_b = (const float*)d_in[13];
    int N = in_sizes[0] / NF_ATOM;   // 200000 (divisible by 64)
    int E = in_sizes[1] / 2;

    char* wsb = (char*)d_ws;
    unsigned short* y2h = (unsigned short*)wsb;                        // N*128 bf16
    unsigned short* zb = (unsigned short*)(wsb + (size_t)N * 256);     // N*128 bf16
    int* epack = (int*)(wsb + (size_t)N * 512);                        // E int
    unsigned short* w1t = (unsigned short*)(wsb + (size_t)N * 512 + (size_t)E * 4);  // 5*65536
    unsigned short* w2t = w1t + 327680;                                // 5*65536
    float* btab = (float*)((char*)w2t + 655360);                       // 5*216*128 f32
    float* sc1 = btab + NLAYER * NCODE * DD;                           // 256
    float* sh1 = sc1 + 256;
    float* sc2 = sh1 + 256;                                            // 128
    float* sh2 = sc2 + 128;
    float* G = sh2 + 128;                                              // 16384
    float* cs = G + DD * DD;                                           // 128
    float* shardG = cs + DD;                                           // 256*16384 (reused per layer)
    float* csS = shardG + (size_t)GRAM_NB * DD * DD;                   // 256*128
    float* shard2 = csS + GRAM_NB * DD;                                // 5 * 32*256 (zeroed)
    size_t zero_f = (size_t)NLAYER * NSHARD * 256;
    int* rsarr = (int*)(shard2 + (size_t)NLAYER * NSHARD * 256);       // N+1
    int* bsum = rsarr + (N + 1);
    int* boff = bsum + 256;
    float invN = 1.0f / (float)N;
    int nbk = (N + 1023) / 1024;

    k_wconv<<<1280, 256, 0, stream>>>(W1, W2, w1t, w2t);
    k_bsumtab<<<(NLAYER * NCODE * DD + 255) / 256, 256, 0, stream>>>(bond_emb, btab);
    hipMemsetAsync(rsarr, 0, ((size_t)N + 1) * 4, stream);
    hipMemsetAsync(shard2, 0, zero_f * sizeof(float), stream);
    k_deg<<<(E + 255) / 256, 256, 0, stream>>>(ei, rsarr, E);
    k_bsum<<<nbk, 256, 0, stream>>>(rsarr, bsum, N);
    k_bscan<<<1, 256, 0, stream>>>(bsum, boff, nbk);
    k_csr<<<nbk, 256, 0, stream>>>(rsarr, boff, rsarr, N, E);
    k_scatter<<<(E + 255) / 256, 256, 0, stream>>>(ei, ea, rsarr, epack, E);
    k_atom<<<(N * 32 + 255) / 256, 256, 0, stream>>>(x, atom_emb, y2h, N);

    int gb = N / 64;
    for (int l = 0; l < NLAYER; ++l) {
        float* sh2d = shard2 + (size_t)l * NSHARD * 256;
        k_zbuild<<<(N * 32 + 255) / 256, 256, 0, stream>>>(y2h, rsarr, epack,
                btab + (size_t)l * NCODE * DD, sc2, sh2, epsv, l, (l == 0) ? 0 : 1, zb, N);
        k_gram<<<GRAM_NB, 256, 0, stream>>>(zb, shardG, csS, N);
        k_gred<<<(DD * DD + DD + 255) / 256, 256, 0, stream>>>(shardG, csS, G, cs);
        k_redG<<<HH, 128, 0, stream>>>(G, cs, w1t + (size_t)l * 65536, b1 + l * HH,
                bn1_g + l * HH, bn1_b + l * HH, invN, sc1, sh1);
        k_fgemm<<<gb, 256, 0, stream>>>(zb, w1t + (size_t)l * 65536, w2t + (size_t)l * 65536,
                sc1, sh1, b2 + l * DD, y2h, sh2d, N);
        k_red<<<1, 128, 0, stream>>>(sh2d, 128, obn_g + l * DD, obn_b + l * DD, invN, sc2, sh2);
    }
    k_bnfinal<<<(int)(((size_t)N * DD / 4 + 255) / 256), 256, 0, stream>>>(
            y2h, sc2, sh2, (float*)d_out, N);
}

// Round 16
// 896.146 us; speedup vs baseline: 1.2335x; 1.0091x over previous
//
#include <hip/hip_runtime.h>

#define NF_ATOM 9
#define NF_BOND 3
#define DD 128
#define HH 256
#define NLAYER 5
#define NSHARD 32
#define NCODE 216
#define GRAM_NB 256

typedef float fv4 __attribute__((ext_vector_type(4)));
typedef __bf16 bfv8 __attribute__((ext_vector_type(8)));
typedef unsigned int uv4 __attribute__((ext_vector_type(4)));

__device__ inline unsigned short f2bf(float f) {
    unsigned int u = __builtin_bit_cast(unsigned int, f);
    u = u + 0x7FFFu + ((u >> 16) & 1u);
    return (unsigned short)(u >> 16);
}
__device__ inline float bf2f(unsigned short s) {
    unsigned int u = ((unsigned int)s) << 16;
    return __builtin_bit_cast(float, u);
}

// ---------- atom encoder: h0 -> bf16 state ----------
__global__ __launch_bounds__(256) void k_atom(const int* __restrict__ x,
        const float* __restrict__ emb, unsigned short* __restrict__ h, int N) {
    int gid = blockIdx.x * 256 + threadIdx.x;
    int n = gid >> 5;
    if (n >= N) return;
    int c = (gid & 31) << 2;
    const int* xr = x + n * NF_ATOM;
    float4 acc = make_float4(0.f, 0.f, 0.f, 0.f);
#pragma unroll
    for (int f = 0; f < NF_ATOM; ++f) {
        int idx = xr[f];
        float4 v = *(const float4*)(emb + ((size_t)(f * 120 + idx) * DD) + c);
        acc.x += v.x; acc.y += v.y; acc.z += v.z; acc.w += v.w;
    }
    ushort4 o;
    o.x = f2bf(acc.x); o.y = f2bf(acc.y); o.z = f2bf(acc.z); o.w = f2bf(acc.w);
    *(ushort4*)(h + (size_t)n * DD + c) = o;
}

// ---------- weight convert: split bf16 (hi + residual lo), chunk-major ----------
__global__ __launch_bounds__(256) void k_wconv(const float* __restrict__ W1,
        const float* __restrict__ W2, unsigned short* __restrict__ W1t,
        unsigned short* __restrict__ W2t) {
    int id = blockIdx.x * 256 + threadIdx.x;
    const int T1 = NLAYER * 4 * 256 * 32;      // 163840
    if (id < T1) {
        int k = id & 31, n = (id >> 5) & 255, kc = (id >> 13) & 3, l = id >> 15;
        int o = id & 32767;
        float w = W1[((size_t)(l * 128 + kc * 32 + k)) * 256 + n];
        unsigned short hi = f2bf(w);
        W1t[(size_t)l * 65536 + o] = hi;
        W1t[(size_t)l * 65536 + 32768 + o] = f2bf(w - bf2f(hi));
    } else {
        int id2 = id - T1;
        if (id2 >= NLAYER * 8 * 128 * 32) return;
        int k = id2 & 31, n = (id2 >> 5) & 127, kc = (id2 >> 12) & 7, l = id2 >> 15;
        int o = id2 & 32767;
        float w = W2[((size_t)(l * 256 + kc * 32 + k)) * 128 + n];
        unsigned short hi = f2bf(w);
        W2t[(size_t)l * 65536 + o] = hi;
        W2t[(size_t)l * 65536 + 32768 + o] = f2bf(w - bf2f(hi));
    }
}

// ---------- bond-sum table ----------
__global__ __launch_bounds__(256) void k_bsumtab(const float* __restrict__ bemb,
        float* __restrict__ tab) {
    int id = blockIdx.x * 256 + threadIdx.x;
    if (id >= NLAYER * NCODE * DD) return;
    int c = id & 127;
    int code = (id >> 7) % NCODE;
    int l = id / (NCODE * DD);
    int a0 = code % 6, a1 = (code / 6) % 6, a2 = code / 36;
    const float* bl = bemb + (size_t)l * NF_BOND * 6 * DD;
    tab[id] = bl[(0 * 6 + a0) * DD + c] + bl[(1 * 6 + a1) * DD + c] + bl[(2 * 6 + a2) * DD + c];
}

// ---------- CSR build ----------
__global__ __launch_bounds__(256) void k_deg(const int* __restrict__ ei, int* __restrict__ deg, int E) {
    int e = blockIdx.x * 256 + threadIdx.x;
    if (e < E) atomicAdd(&deg[ei[E + e]], 1);
}
__global__ __launch_bounds__(256) void k_bsum(const int* __restrict__ deg, int* __restrict__ bsum, int N) {
    __shared__ int red[256];
    int t = threadIdx.x, b = blockIdx.x;
    int i0 = b * 1024 + t * 4;
    int s = 0;
#pragma unroll
    for (int j = 0; j < 4; ++j) if (i0 + j < N) s += deg[i0 + j];
    red[t] = s; __syncthreads();
    for (int off = 128; off > 0; off >>= 1) {
        if (t < off) red[t] += red[t + off];
        __syncthreads();
    }
    if (t == 0) bsum[b] = red[0];
}
__global__ __launch_bounds__(256) void k_bscan(const int* __restrict__ bsum, int* __restrict__ boff, int nb) {
    __shared__ int ts[256];
    int t = threadIdx.x;
    int v = (t < nb) ? bsum[t] : 0;
    ts[t] = v; __syncthreads();
    for (int off = 1; off < 256; off <<= 1) {
        int u = (t >= off) ? ts[t - off] : 0;
        __syncthreads();
        ts[t] += u;
        __syncthreads();
    }
    if (t < nb) boff[t] = ts[t] - v;   // exclusive
}
__global__ __launch_bounds__(256) void k_csr(const int* deg, const int* __restrict__ boff,
        int* rs, int N, int E) {
    __shared__ int ts[256];
    int t = threadIdx.x, b = blockIdx.x;
    int i0 = b * 1024 + t * 4;
    int d[4];
#pragma unroll
    for (int j = 0; j < 4; ++j) d[j] = (i0 + j < N) ? deg[i0 + j] : 0;
    int tsum = d[0] + d[1] + d[2] + d[3];
    ts[t] = tsum; __syncthreads();
    for (int off = 1; off < 256; off <<= 1) {
        int u = (t >= off) ? ts[t - off] : 0;
        __syncthreads();
        ts[t] += u;
        __syncthreads();
    }
    int base = boff[b] + ts[t] - tsum;
    int p = 0;
#pragma unroll
    for (int j = 0; j < 4; ++j) {
        int dj = d[j];
        if (i0 + j < N) rs[i0 + j] = base + p;
        p += dj;
    }
    if (b == 0 && t == 0) rs[N] = E;
}
// packed record: src (18 bits) | code6 << 18
__global__ __launch_bounds__(256) void k_scatter(const int* __restrict__ ei,
        const int* __restrict__ ea, int* __restrict__ rs, int* __restrict__ epack, int E) {
    int e = blockIdx.x * 256 + threadIdx.x;
    if (e < E) {
        int pos = atomicAdd(&rs[ei[E + e]], 1);
        int code = ea[e * 3 + 0] + 6 * ea[e * 3 + 1] + 36 * ea[e * 3 + 2];
        epack[pos] = ei[e] | (code << 18);
    }
}

// ---------- BN2 shard reduce -> scale/shift ----------
__global__ void k_red(const float* __restrict__ sh, int C, const float* __restrict__ bng,
        const float* __restrict__ bnb, float invN,
        float* __restrict__ sc_out, float* __restrict__ sh_out) {
    int t = threadIdx.x;
    if (t >= C) return;
    float a = 0.f, qq = 0.f;
#pragma unroll
    for (int s = 0; s < NSHARD; ++s) {
        a += sh[s * 2 * C + t];
        qq += sh[s * 2 * C + C + t];
    }
    float mu = a * invN;
    float var = qq * invN - mu * mu;
    float r = rsqrtf(var + 1e-5f);
    float sc = bng[t] * r;
    sc_out[t] = sc; sh_out[t] = bnb[t] - mu * sc;
}

// ---------- zbuild ----------
__device__ inline void edge_acc(ushort4 hv, float4 bv, float4 sc, float4 sh, int mode, float* ag) {
    float h0 = bf2f(hv.x), h1 = bf2f(hv.y), h2 = bf2f(hv.z), h3 = bf2f(hv.w);
    if (mode) {
        h0 = fmaxf(h0 * sc.x + sh.x, 0.f); h1 = fmaxf(h1 * sc.y + sh.y, 0.f);
        h2 = fmaxf(h2 * sc.z + sh.z, 0.f); h3 = fmaxf(h3 * sc.w + sh.w, 0.f);
    }
    ag[0] += fmaxf(h0 + bv.x, 0.f); ag[1] += fmaxf(h1 + bv.y, 0.f);
    ag[2] += fmaxf(h2 + bv.z, 0.f); ag[3] += fmaxf(h3 + bv.w, 0.f);
}

__global__ __launch_bounds__(256) void k_zbuild(const unsigned short* __restrict__ y2h,
        const int* __restrict__ rs, const int* __restrict__ epack,
        const float* __restrict__ btab, const float* __restrict__ sctab,
        const float* __restrict__ shtab, const float* __restrict__ epsv,
        int l, int mode, unsigned short* __restrict__ z, int N) {
    int gid = blockIdx.x * 256 + threadIdx.x;
    int n = gid >> 5;
    if (n >= N) return;
    int c = (gid & 31) << 2;
    float4 sc4 = make_float4(1.f, 1.f, 1.f, 1.f), sh4 = make_float4(0.f, 0.f, 0.f, 0.f);
    if (mode) { sc4 = *(const float4*)(sctab + c); sh4 = *(const float4*)(shtab + c); }
    int p0 = (n == 0) ? 0 : rs[n - 1];
    int p1 = rs[n];
    float ag[4] = {0.f, 0.f, 0.f, 0.f};
    int p = p0;
    for (; p + 2 <= p1; p += 2) {
        int rec0 = epack[p], rec1 = epack[p + 1];
        int s0 = rec0 & 0x3FFFF, s1 = rec1 & 0x3FFFF;
        int c0 = ((unsigned int)rec0) >> 18, c1 = ((unsigned int)rec1) >> 18;
        ushort4 h0 = *(const ushort4*)(y2h + (size_t)s0 * DD + c);
        ushort4 h1 = *(const ushort4*)(y2h + (size_t)s1 * DD + c);
        float4 b0 = *(const float4*)(btab + (size_t)c0 * DD + c);
        float4 b1 = *(const float4*)(btab + (size_t)c1 * DD + c);
        edge_acc(h0, b0, sc4, sh4, mode, ag);
        edge_acc(h1, b1, sc4, sh4, mode, ag);
    }
    if (p < p1) {
        int rec = epack[p];
        int s0 = rec & 0x3FFFF;
        int c0 = ((unsigned int)rec) >> 18;
        ushort4 h0 = *(const ushort4*)(y2h + (size_t)s0 * DD + c);
        float4 b0 = *(const float4*)(btab + (size_t)c0 * DD + c);
        edge_acc(h0, b0, sc4, sh4, mode, ag);
    }
    float ep = 1.0f + epsv[l];
    ushort4 sv = *(const ushort4*)(y2h + (size_t)n * DD + c);
    float hz[4] = {bf2f(sv.x), bf2f(sv.y), bf2f(sv.z), bf2f(sv.w)};
    if (mode) {
        hz[0] = fmaxf(hz[0] * sc4.x + sh4.x, 0.f);
        hz[1] = fmaxf(hz[1] * sc4.y + sh4.y, 0.f);
        hz[2] = fmaxf(hz[2] * sc4.z + sh4.z, 0.f);
        hz[3] = fmaxf(hz[3] * sc4.w + sh4.w, 0.f);
    }
    ushort4 o;
    o.x = f2bf(ep * hz[0] + ag[0]);
    o.y = f2bf(ep * hz[1] + ag[1]);
    o.z = f2bf(ep * hz[2] + ag[2]);
    o.w = f2bf(ep * hz[3] + ag[3]);
    *(ushort4*)(z + (size_t)n * DD + c) = o;
}

// ---------- Gram: per-block partial G = Z^T Z + colsum, direct stores (no atomics) ----------
__global__ __launch_bounds__(256) void k_gram(const unsigned short* __restrict__ z,
        float* __restrict__ shardG, float* __restrict__ csS, int N) {
    __shared__ uv4 zT[128 * 8];   // transposed tile [ch][8 granules of 8 rows], 16KB
    int tid = threadIdx.x;
    int lane = tid & 63, wave = tid >> 6, lq = lane >> 4, lr = lane & 15;
    int cg = tid & 15;
    float cs[8] = {0, 0, 0, 0, 0, 0, 0, 0};
    fv4 acc[2][8];
#pragma unroll
    for (int ti = 0; ti < 2; ++ti)
#pragma unroll
        for (int tj = 0; tj < 8; ++tj) acc[ti][tj] = (fv4){0.f, 0.f, 0.f, 0.f};

    int ntile = N >> 6;
    for (int t = blockIdx.x; t < ntile; t += GRAM_NB) {
        const unsigned short* zt0 = z + ((size_t)t << 6) * DD;
        __syncthreads();
#pragma unroll
        for (int i = 0; i < 2; ++i) {
            int rp = i * 16 + (tid >> 4);
            int r0 = rp * 2;
            uv4 a = *(const uv4*)(zt0 + (size_t)r0 * DD + cg * 8);
            uv4 b = *(const uv4*)(zt0 + (size_t)(r0 + 1) * DD + cg * 8);
            int g = rp >> 2;
            int eo = rp & 3;
#pragma unroll
            for (int j = 0; j < 4; ++j) {
                unsigned int lo0 = a[j] & 0xFFFFu, hi0 = a[j] >> 16;
                unsigned int lo1 = b[j] & 0xFFFFu, hi1 = b[j] >> 16;
                cs[2 * j] += bf2f((unsigned short)lo0) + bf2f((unsigned short)lo1);
                cs[2 * j + 1] += bf2f((unsigned short)hi0) + bf2f((unsigned short)hi1);
                int ch0 = cg * 8 + 2 * j, ch1 = ch0 + 1;
                int s0 = ch0 * 8 + (g ^ ((ch0 ^ (ch0 >> 3)) & 7));
                int s1 = ch1 * 8 + (g ^ ((ch1 ^ (ch1 >> 3)) & 7));
                ((unsigned int*)zT)[s0 * 4 + eo] = lo0 | (lo1 << 16);
                ((unsigned int*)zT)[s1 * 4 + eo] = hi0 | (hi1 << 16);
            }
        }
        __syncthreads();
#pragma unroll
        for (int ks = 0; ks < 2; ++ks) {
            bfv8 af[2], bfr[8];
#pragma unroll
            for (int ti = 0; ti < 2; ++ti) {
                int ch = wave * 32 + ti * 16 + lr;
                af[ti] = __builtin_bit_cast(bfv8, zT[ch * 8 + ((ks * 4 + lq) ^ ((ch ^ (ch >> 3)) & 7))]);
            }
#pragma unroll
            for (int tj = 0; tj < 8; ++tj) {
                int ch = tj * 16 + lr;
                bfr[tj] = __builtin_bit_cast(bfv8, zT[ch * 8 + ((ks * 4 + lq) ^ ((ch ^ (ch >> 3)) & 7))]);
            }
#pragma unroll
            for (int ti = 0; ti < 2; ++ti)
#pragma unroll
                for (int tj = 0; tj < 8; ++tj)
                    acc[ti][tj] = __builtin_amdgcn_mfma_f32_16x16x32_bf16(af[ti], bfr[tj], acc[ti][tj], 0, 0, 0);
        }
    }
    float* gsh = shardG + (size_t)blockIdx.x * (DD * DD);
#pragma unroll
    for (int ti = 0; ti < 2; ++ti) {
        int gi = wave * 32 + ti * 16 + lq * 4;
#pragma unroll
        for (int tj = 0; tj < 8; ++tj) {
            int gj = tj * 16 + lr;
#pragma unroll
            for (int r = 0; r < 4; ++r)
                gsh[(size_t)(gi + r) * DD + gj] = acc[ti][tj][r];
        }
    }
    __syncthreads();
    float* red = (float*)zT;
#pragma unroll
    for (int j = 0; j < 8; ++j) red[tid * 8 + j] = cs[j];
    __syncthreads();
    if (tid < 128) {
        int cgg = tid >> 3, j = tid & 7;
        float a = 0.f;
#pragma unroll
        for (int k = 0; k < 16; ++k) a += red[(k * 16 + cgg) * 8 + j];
        csS[blockIdx.x * DD + cgg * 8 + j] = a;
    }
}

// ---------- reduce G/cs shards to dense ----------
__global__ __launch_bounds__(256) void k_gred(const float* __restrict__ shardG,
        const float* __restrict__ csS, float* __restrict__ G, float* __restrict__ cs) {
    int idx = blockIdx.x * 256 + threadIdx.x;
    if (idx < DD * DD) {
        float a = 0.f;
#pragma unroll 8
        for (int s = 0; s < GRAM_NB; ++s) a += shardG[(size_t)s * DD * DD + idx];
        G[idx] = a;
    } else if (idx < DD * DD + DD) {
        int t = idx - DD * DD;
        float a = 0.f;
#pragma unroll 8
        for (int s = 0; s < GRAM_NB; ++s) a += csS[s * DD + t];
        cs[t] = a;
    }
}

// ---------- BN1 stats from Gram ----------
__global__ __launch_bounds__(128) void k_redG(const float* __restrict__ G,
        const float* __restrict__ cs, const unsigned short* __restrict__ W1l,
        const float* __restrict__ b1, const float* __restrict__ bng,
        const float* __restrict__ bnb, float invN,
        float* __restrict__ sc_out, float* __restrict__ sh_out) {
    __shared__ float wv[128];
    __shared__ float redA[128], redB[128];
    int j = blockIdx.x;
    int t = threadIdx.x;
    int kc = t >> 5, kk = t & 31;
    int o = kc * 8192 + j * 32 + kk;
    float w_t = bf2f(W1l[o]) + bf2f(W1l[32768 + o]);
    wv[t] = w_t;
    __syncthreads();
    const float4* Gr = (const float4*)(G + (size_t)t * DD);
    float d = 0.f;
#pragma unroll
    for (int i = 0; i < 32; ++i) {
        float4 g4 = Gr[i];
        d += g4.x * wv[i * 4] + g4.y * wv[i * 4 + 1] + g4.z * wv[i * 4 + 2] + g4.w * wv[i * 4 + 3];
    }
    redA[t] = w_t * d;
    redB[t] = cs[t] * w_t;
    __syncthreads();
    for (int off = 64; off > 0; off >>= 1) {
        if (t < off) { redA[t] += redA[t + off]; redB[t] += redB[t + off]; }
        __syncthreads();
    }
    if (t == 0) {
        float bj = b1[j];
        float csw = redB[0];
        float mean = csw * invN + bj;
        float ey2 = redA[0] * invN + 2.f * bj * csw * invN + bj * bj;
        float var = ey2 - mean * mean;
        float r = rsqrtf(var + 1e-5f);
        float sc = bng[j] * r;
        sc_out[j] = sc;
        sh_out[j] = bnb[j] - mean * sc + bj * sc;
    }
}

// ---------- fused GEMM: weights direct global->register (no weight LDS), 3 barriers ----------
// LDS: zt 16KB (phase1) aliased by at 32KB (phase2); total 32KB
__global__ __launch_bounds__(256, 3) void k_fgemm(const unsigned short* __restrict__ z,
        const unsigned short* __restrict__ W1l, const unsigned short* __restrict__ W2l,
        const float* __restrict__ sc1, const float* __restrict__ sh1,
        const float* __restrict__ bias2,
        unsigned short* __restrict__ y2h, float* __restrict__ shard, int N) {
    __shared__ uv4 smem[2048];           // 32KB
    uv4* zt = smem;                      // phase1: [64*16] 16KB
    uv4* at = smem;                      // phase2: [64*32] 32KB
    int tid = threadIdx.x;
    int row0 = blockIdx.x * 64;
    int wave = tid >> 6, lane = tid & 63, lq = lane >> 4, lr = lane & 15;
    int rbase = tid >> 4, gz = tid & 15;

    // stage z tile (shared) + prefetch W1 kc0 fragments (per-lane, contiguous 16B)
    uv4 zr[4];
#pragma unroll
    for (int i = 0; i < 4; ++i)
        zr[i] = *(const uv4*)(z + (size_t)(row0 + i * 16 + rbase) * DD + gz * 8);
    const uv4* w1src = (const uv4*)W1l;      // hi at (kc*256+n)*4+lq, lo at +4096
    uv4 wh[2][4], wl[2][4];
#pragma unroll
    for (int mc = 0; mc < 4; ++mc) {
        int col = wave * 64 + mc * 16 + lr;
        wh[0][mc] = w1src[(size_t)col * 4 + lq];
        wl[0][mc] = w1src[4096 + (size_t)col * 4 + lq];
    }
#pragma unroll
    for (int i = 0; i < 4; ++i) {
        int row = i * 16 + rbase;
        zt[row * 16 + (gz ^ (row & 15))] = zr[i];
    }
    __syncthreads();   // barrier 1/3: zt visible

    fv4 acc1[4][4];
#pragma unroll
    for (int mc = 0; mc < 4; ++mc)
#pragma unroll
        for (int nr = 0; nr < 4; ++nr) acc1[mc][nr] = (fv4){0.f, 0.f, 0.f, 0.f};

#pragma unroll
    for (int kc = 0; kc < 4; ++kc) {
        const int cur = kc & 1, nxt = cur ^ 1;
        if (kc < 3) {
#pragma unroll
            for (int mc = 0; mc < 4; ++mc) {
                int col = wave * 64 + mc * 16 + lr;
                wh[nxt][mc] = w1src[(size_t)((kc + 1) * 256 + col) * 4 + lq];
                wl[nxt][mc] = w1src[4096 + (size_t)((kc + 1) * 256 + col) * 4 + lq];
            }
        }
        bfv8 zf[4];
#pragma unroll
        for (int nr = 0; nr < 4; ++nr) {
            int row = nr * 16 + lr;
            zf[nr] = __builtin_bit_cast(bfv8, zt[row * 16 + ((kc * 4 + lq) ^ (row & 15))]);
        }
#pragma unroll
        for (int mc = 0; mc < 4; ++mc)
#pragma unroll
            for (int nr = 0; nr < 4; ++nr) {
                acc1[mc][nr] = __builtin_amdgcn_mfma_f32_16x16x32_bf16(
                        __builtin_bit_cast(bfv8, wh[cur][mc]), zf[nr], acc1[mc][nr], 0, 0, 0);
                acc1[mc][nr] = __builtin_amdgcn_mfma_f32_16x16x32_bf16(
                        __builtin_bit_cast(bfv8, wl[cur][mc]), zf[nr], acc1[mc][nr], 0, 0, 0);
            }
    }
    __syncthreads();   // barrier 2/3: all zt reads done before at writes

    // prefetch W2 kc0 fragments
    const uv4* w2src = (const uv4*)W2l;      // hi at (kc*128+n)*4+lq, lo at +4096
    uv4 w2h[2][2], w2l[2][2];
#pragma unroll
    for (int nb = 0; nb < 2; ++nb) {
        int col = wave * 32 + nb * 16 + lr;
        w2h[0][nb] = w2src[(size_t)col * 4 + lq];
        w2l[0][nb] = w2src[4096 + (size_t)col * 4 + lq];
    }

    // epilogue1: bn1-apply + relu + bf16 pack -> at tile
#pragma unroll
    for (int mc = 0; mc < 4; ++mc) {
        int ycol0 = wave * 64 + mc * 16 + lq * 4;
        float4 s4 = *(const float4*)(sc1 + ycol0);
        float4 h4 = *(const float4*)(sh1 + ycol0);
        int gg = wave * 8 + mc * 2 + (lq >> 1);
#pragma unroll
        for (int nr = 0; nr < 4; ++nr) {
            int zrow = nr * 16 + lr;
            float v0 = fmaxf(acc1[mc][nr][0] * s4.x + h4.x, 0.f);
            float v1 = fmaxf(acc1[mc][nr][1] * s4.y + h4.y, 0.f);
            float v2 = fmaxf(acc1[mc][nr][2] * s4.z + h4.z, 0.f);
            float v3 = fmaxf(acc1[mc][nr][3] * s4.w + h4.w, 0.f);
            uint2 pk;
            pk.x = (unsigned int)f2bf(v0) | ((unsigned int)f2bf(v1) << 16);
            pk.y = (unsigned int)f2bf(v2) | ((unsigned int)f2bf(v3) << 16);
            int gs = gg ^ (zrow & 15);
            ((uint2*)at)[(zrow * 32 + gs) * 2 + (lq & 1)] = pk;
        }
    }
    __syncthreads();   // barrier 3/3: at visible

    fv4 acc2[4][2];
#pragma unroll
    for (int m = 0; m < 4; ++m) { acc2[m][0] = (fv4){0.f,0.f,0.f,0.f}; acc2[m][1] = (fv4){0.f,0.f,0.f,0.f}; }

#pragma unroll
    for (int kc = 0; kc < 8; ++kc) {
        const int cur = kc & 1, nxt = cur ^ 1;
        if (kc < 7) {
#pragma unroll
            for (int nb = 0; nb < 2; ++nb) {
                int col = wave * 32 + nb * 16 + lr;
                w2h[nxt][nb] = w2src[(size_t)((kc + 1) * 128 + col) * 4 + lq];
                w2l[nxt][nb] = w2src[4096 + (size_t)((kc + 1) * 128 + col) * 4 + lq];
            }
        }
        bfv8 a[4];
#pragma unroll
        for (int m = 0; m < 4; ++m) {
            int row = m * 16 + lr;
            a[m] = __builtin_bit_cast(bfv8, at[row * 32 + ((kc * 4 + lq) ^ (row & 15))]);
        }
#pragma unroll
        for (int m = 0; m < 4; ++m)
#pragma unroll
            for (int nb = 0; nb < 2; ++nb) {
                acc2[m][nb] = __builtin_amdgcn_mfma_f32_16x16x32_bf16(
                        a[m], __builtin_bit_cast(bfv8, w2h[cur][nb]), acc2[m][nb], 0, 0, 0);
                acc2[m][nb] = __builtin_amdgcn_mfma_f32_16x16x32_bf16(
                        a[m], __builtin_bit_cast(bfv8, w2l[cur][nb]), acc2[m][nb], 0, 0, 0);
            }
    }

    float bv[2], s[2], q[2];
#pragma unroll
    for (int nb = 0; nb < 2; ++nb) {
        bv[nb] = bias2[wave * 32 + nb * 16 + lr];
        s[nb] = 0.f; q[nb] = 0.f;
    }
#pragma unroll
    for (int m = 0; m < 4; ++m)
#pragma unroll
        for (int nb = 0; nb < 2; ++nb) {
            int col = wave * 32 + nb * 16 + lr;
#pragma unroll
            for (int r = 0; r < 4; ++r) {
                float v = acc2[m][nb][r] + bv[nb];
                unsigned short ub = f2bf(v);
                float vr = bf2f(ub);
                int row = row0 + m * 16 + lq * 4 + r;
                y2h[(size_t)row * DD + col] = ub;
                s[nb] += vr; q[nb] += vr * vr;
            }
        }
#pragma unroll
    for (int nb = 0; nb < 2; ++nb) {
        s[nb] += __shfl_xor(s[nb], 16); s[nb] += __shfl_xor(s[nb], 32);
        q[nb] += __shfl_xor(q[nb], 16); q[nb] += __shfl_xor(q[nb], 32);
    }
    if (lane < 16) {
        int shb = (blockIdx.x & (NSHARD - 1)) * 256;
#pragma unroll
        for (int nb = 0; nb < 2; ++nb) {
            int col = wave * 32 + nb * 16 + lr;
            atomicAdd(shard + shb + col, s[nb]);
            atomicAdd(shard + shb + 128 + col, q[nb]);
        }
    }
}

// ---------- final: out = relu(bn2(y2h)) -> f32 ----------
__global__ __launch_bounds__(256) void k_bnfinal(const unsigned short* __restrict__ y2h,
        const float* __restrict__ sc2, const float* __restrict__ sh2,
        float* __restrict__ out, int N) {
    size_t base = ((size_t)blockIdx.x * 256 + threadIdx.x) * 4;
    if (base >= (size_t)N * DD) return;
    int c = (int)(base & (DD - 1));
    ushort4 v = *(const ushort4*)(y2h + base);
    float4 s = *(const float4*)(sc2 + c);
    float4 t = *(const float4*)(sh2 + c);
    float4 o;
    o.x = fmaxf(bf2f(v.x) * s.x + t.x, 0.f);
    o.y = fmaxf(bf2f(v.y) * s.y + t.y, 0.f);
    o.z = fmaxf(bf2f(v.z) * s.z + t.z, 0.f);
    o.w = fmaxf(bf2f(v.w) * s.w + t.w, 0.f);
    *(float4*)(out + base) = o;
}

extern "C" void kernel_launch(void* const* d_in, const int* in_sizes, int n_in,
                              void* d_out, int out_size, void* d_ws, size_t ws_size,
                              hipStream_t stream) {
    const int* x = (const int*)d_in[0];
    const int* ei = (const int*)d_in[1];
    const int* ea = (const int*)d_in[2];
    const float* atom_emb = (const float*)d_in[3];
    const float* bond_emb = (const float*)d_in[4];
    const float* W1 = (const float*)d_in[5];
    const float* b1 = (const float*)d_in[6];
    const float* bn1_g = (const float*)d_in[7];
    const float* bn1_b = (const float*)d_in[8];
    const float* W2 = (const float*)d_in[9];
    const float* b2 = (const float*)d_in[10];
    const float* epsv = (const float*)d_in[11];
    const float* obn_g = (const float*)d_in[12];
    const float* obn_b = (const float*)d_in[13];
    int N = in_sizes[0] / NF_ATOM;   // 200000 (divisible by 64)
    int E = in_sizes[1] / 2;

    char* wsb = (char*)d_ws;
    unsigned short* y2h = (unsigned short*)wsb;                        // N*128 bf16
    unsigned short* zb = (unsigned short*)(wsb + (size_t)N * 256);     // N*128 bf16
    int* epack = (int*)(wsb + (size_t)N * 512);                        // E int
    unsigned short* w1t = (unsigned short*)(wsb + (size_t)N * 512 + (size_t)E * 4);  // 5*65536
    unsigned short* w2t = w1t + 327680;                                // 5*65536
    float* btab = (float*)((char*)w2t + 655360);                       // 5*216*128 f32
    float* sc1 = btab + NLAYER * NCODE * DD;                           // 256
    float* sh1 = sc1 + 256;
    float* sc2 = sh1 + 256;                                            // 128
    float* sh2 = sc2 + 128;
    float* G = sh2 + 128;                                              // 16384
    float* cs = G + DD * DD;                                           // 128
    float* shardG = cs + DD;                                           // 256*16384 (reused per layer)
    float* csS = shardG + (size_t)GRAM_NB * DD * DD;                   // 256*128
    float* shard2 = csS + GRAM_NB * DD;                                // 5 * 32*256 (zeroed)
    size_t zero_f = (size_t)NLAYER * NSHARD * 256;
    int* rsarr = (int*)(shard2 + (size_t)NLAYER * NSHARD * 256);       // N+1
    int* bsum = rsarr + (N + 1);
    int* boff = bsum + 256;
    float invN = 1.0f / (float)N;
    int nbk = (N + 1023) / 1024;

    k_wconv<<<1280, 256, 0, stream>>>(W1, W2, w1t, w2t);
    k_bsumtab<<<(NLAYER * NCODE * DD + 255) / 256, 256, 0, stream>>>(bond_emb, btab);
    hipMemsetAsync(rsarr, 0, ((size_t)N + 1) * 4, stream);
    hipMemsetAsync(shard2, 0, zero_f * sizeof(float), stream);
    k_deg<<<(E + 255) / 256, 256, 0, stream>>>(ei, rsarr, E);
    k_bsum<<<nbk, 256, 0, stream>>>(rsarr, bsum, N);
    k_bscan<<<1, 256, 0, stream>>>(bsum, boff, nbk);
    k_csr<<<nbk, 256, 0, stream>>>(rsarr, boff, rsarr, N, E);
    k_scatter<<<(E + 255) / 256, 256, 0, stream>>>(ei, ea, rsarr, epack, E);
    k_atom<<<(N * 32 + 255) / 256, 256, 0, stream>>>(x, atom_emb, y2h, N);

    int gb = N / 64;
    for (int l = 0; l < NLAYER; ++l) {
        float* sh2d = shard2 + (size_t)l * NSHARD * 256;
        k_zbuild<<<(N * 32 + 255) / 256, 256, 0, stream>>>(y2h, rsarr, epack,
                btab + (size_t)l * NCODE * DD, sc2, sh2, epsv, l, (l == 0) ? 0 : 1, zb, N);
        k_gram<<<GRAM_NB, 256, 0, stream>>>(zb, shardG, csS, N);
        k_gred<<<(DD * DD + DD + 255) / 256, 256, 0, stream>>>(shardG, csS, G, cs);
        k_redG<<<HH, 128, 0, stream>>>(G, cs, w1t + (size_t)l * 65536, b1 + l * HH,
                bn1_g + l * HH, bn1_b + l * HH, invN, sc1, sh1);
        k_fgemm<<<gb, 256, 0, stream>>>(zb, w1t + (size_t)l * 65536, w2t + (size_t)l * 65536,
                sc1, sh1, b2 + l * DD, y2h, sh2d, N);
        k_red<<<1, 128, 0, stream>>>(sh2d, 128, obn_g + l * DD, obn_b + l * DD, invN, sc2, sh2);
    }
    k_bnfinal<<<(int)(((size_t)N * DD / 4 + 255) / 256), 256, 0, stream>>>(
            y2h, sc2, sh2, (float*)d_out, N);
}

// Round 17
// 881.201 us; speedup vs baseline: 1.2544x; 1.0170x over previous
//
#include <hip/hip_runtime.h>

#define NF_ATOM 9
#define NF_BOND 3
#define DD 128
#define HH 256
#define NLAYER 5
#define NSHARD 32
#define NCODE 216
#define GRAM_NB 256

typedef float fv4 __attribute__((ext_vector_type(4)));
typedef __bf16 bfv8 __attribute__((ext_vector_type(8)));
typedef unsigned int uv4 __attribute__((ext_vector_type(4)));

__device__ inline unsigned short f2bf(float f) {
    __bf16 b = (__bf16)f;                  // HW RTNE convert (v_cvt_pk when paired)
    return __builtin_bit_cast(unsigned short, b);
}
__device__ inline float bf2f(unsigned short s) {
    unsigned int u = ((unsigned int)s) << 16;
    return __builtin_bit_cast(float, u);
}

// ---------- atom encoder: h0 -> bf16 state ----------
__global__ __launch_bounds__(256) void k_atom(const int* __restrict__ x,
        const float* __restrict__ emb, unsigned short* __restrict__ h, int N) {
    int gid = blockIdx.x * 256 + threadIdx.x;
    int n = gid >> 5;
    if (n >= N) return;
    int c = (gid & 31) << 2;
    const int* xr = x + n * NF_ATOM;
    float4 acc = make_float4(0.f, 0.f, 0.f, 0.f);
#pragma unroll
    for (int f = 0; f < NF_ATOM; ++f) {
        int idx = xr[f];
        float4 v = *(const float4*)(emb + ((size_t)(f * 120 + idx) * DD) + c);
        acc.x += v.x; acc.y += v.y; acc.z += v.z; acc.w += v.w;
    }
    ushort4 o;
    o.x = f2bf(acc.x); o.y = f2bf(acc.y); o.z = f2bf(acc.z); o.w = f2bf(acc.w);
    *(ushort4*)(h + (size_t)n * DD + c) = o;
}

// ---------- weight convert: split bf16 (hi + residual lo), chunk-major ----------
__global__ __launch_bounds__(256) void k_wconv(const float* __restrict__ W1,
        const float* __restrict__ W2, unsigned short* __restrict__ W1t,
        unsigned short* __restrict__ W2t) {
    int id = blockIdx.x * 256 + threadIdx.x;
    const int T1 = NLAYER * 4 * 256 * 32;      // 163840
    if (id < T1) {
        int k = id & 31, n = (id >> 5) & 255, kc = (id >> 13) & 3, l = id >> 15;
        int o = id & 32767;
        float w = W1[((size_t)(l * 128 + kc * 32 + k)) * 256 + n];
        unsigned short hi = f2bf(w);
        W1t[(size_t)l * 65536 + o] = hi;
        W1t[(size_t)l * 65536 + 32768 + o] = f2bf(w - bf2f(hi));
    } else {
        int id2 = id - T1;
        if (id2 >= NLAYER * 8 * 128 * 32) return;
        int k = id2 & 31, n = (id2 >> 5) & 127, kc = (id2 >> 12) & 7, l = id2 >> 15;
        int o = id2 & 32767;
        float w = W2[((size_t)(l * 256 + kc * 32 + k)) * 128 + n];
        unsigned short hi = f2bf(w);
        W2t[(size_t)l * 65536 + o] = hi;
        W2t[(size_t)l * 65536 + 32768 + o] = f2bf(w - bf2f(hi));
    }
}

// ---------- bond-sum table ----------
__global__ __launch_bounds__(256) void k_bsumtab(const float* __restrict__ bemb,
        float* __restrict__ tab) {
    int id = blockIdx.x * 256 + threadIdx.x;
    if (id >= NLAYER * NCODE * DD) return;
    int c = id & 127;
    int code = (id >> 7) % NCODE;
    int l = id / (NCODE * DD);
    int a0 = code % 6, a1 = (code / 6) % 6, a2 = code / 36;
    const float* bl = bemb + (size_t)l * NF_BOND * 6 * DD;
    tab[id] = bl[(0 * 6 + a0) * DD + c] + bl[(1 * 6 + a1) * DD + c] + bl[(2 * 6 + a2) * DD + c];
}

// ---------- CSR build ----------
__global__ __launch_bounds__(256) void k_deg(const int* __restrict__ ei, int* __restrict__ deg, int E) {
    int e = blockIdx.x * 256 + threadIdx.x;
    if (e < E) atomicAdd(&deg[ei[E + e]], 1);
}
__global__ __launch_bounds__(256) void k_bsum(const int* __restrict__ deg, int* __restrict__ bsum, int N) {
    __shared__ int red[256];
    int t = threadIdx.x, b = blockIdx.x;
    int i0 = b * 1024 + t * 4;
    int s = 0;
#pragma unroll
    for (int j = 0; j < 4; ++j) if (i0 + j < N) s += deg[i0 + j];
    red[t] = s; __syncthreads();
    for (int off = 128; off > 0; off >>= 1) {
        if (t < off) red[t] += red[t + off];
        __syncthreads();
    }
    if (t == 0) bsum[b] = red[0];
}
__global__ __launch_bounds__(256) void k_bscan(const int* __restrict__ bsum, int* __restrict__ boff, int nb) {
    __shared__ int ts[256];
    int t = threadIdx.x;
    int v = (t < nb) ? bsum[t] : 0;
    ts[t] = v; __syncthreads();
    for (int off = 1; off < 256; off <<= 1) {
        int u = (t >= off) ? ts[t - off] : 0;
        __syncthreads();
        ts[t] += u;
        __syncthreads();
    }
    if (t < nb) boff[t] = ts[t] - v;   // exclusive
}
__global__ __launch_bounds__(256) void k_csr(const int* deg, const int* __restrict__ boff,
        int* rs, int N, int E) {
    __shared__ int ts[256];
    int t = threadIdx.x, b = blockIdx.x;
    int i0 = b * 1024 + t * 4;
    int d[4];
#pragma unroll
    for (int j = 0; j < 4; ++j) d[j] = (i0 + j < N) ? deg[i0 + j] : 0;
    int tsum = d[0] + d[1] + d[2] + d[3];
    ts[t] = tsum; __syncthreads();
    for (int off = 1; off < 256; off <<= 1) {
        int u = (t >= off) ? ts[t - off] : 0;
        __syncthreads();
        ts[t] += u;
        __syncthreads();
    }
    int base = boff[b] + ts[t] - tsum;
    int p = 0;
#pragma unroll
    for (int j = 0; j < 4; ++j) {
        int dj = d[j];
        if (i0 + j < N) rs[i0 + j] = base + p;
        p += dj;
    }
    if (b == 0 && t == 0) rs[N] = E;
}
// packed record: src (18 bits) | code6 << 18
__global__ __launch_bounds__(256) void k_scatter(const int* __restrict__ ei,
        const int* __restrict__ ea, int* __restrict__ rs, int* __restrict__ epack, int E) {
    int e = blockIdx.x * 256 + threadIdx.x;
    if (e < E) {
        int pos = atomicAdd(&rs[ei[E + e]], 1);
        int code = ea[e * 3 + 0] + 6 * ea[e * 3 + 1] + 36 * ea[e * 3 + 2];
        epack[pos] = ei[e] | (code << 18);
    }
}

// ---------- BN2 shard reduce -> scale/shift ----------
__global__ void k_red(const float* __restrict__ sh, int C, const float* __restrict__ bng,
        const float* __restrict__ bnb, float invN,
        float* __restrict__ sc_out, float* __restrict__ sh_out) {
    int t = threadIdx.x;
    if (t >= C) return;
    float a = 0.f, qq = 0.f;
#pragma unroll
    for (int s = 0; s < NSHARD; ++s) {
        a += sh[s * 2 * C + t];
        qq += sh[s * 2 * C + C + t];
    }
    float mu = a * invN;
    float var = qq * invN - mu * mu;
    float r = rsqrtf(var + 1e-5f);
    float sc = bng[t] * r;
    sc_out[t] = sc; sh_out[t] = bnb[t] - mu * sc;
}

// ---------- zbuild: 16 lanes x 8 channels per node ----------
__device__ inline void edge_acc8(uv4 hv, const float* bt, const float* sc,
        const float* sh, int mode, float* ag) {
#pragma unroll
    for (int j = 0; j < 4; ++j) {
        float h0 = bf2f((unsigned short)(hv[j] & 0xFFFFu));
        float h1 = bf2f((unsigned short)(hv[j] >> 16));
        if (mode) {
            h0 = fmaxf(h0 * sc[2 * j] + sh[2 * j], 0.f);
            h1 = fmaxf(h1 * sc[2 * j + 1] + sh[2 * j + 1], 0.f);
        }
        ag[2 * j] += fmaxf(h0 + bt[2 * j], 0.f);
        ag[2 * j + 1] += fmaxf(h1 + bt[2 * j + 1], 0.f);
    }
}

__global__ __launch_bounds__(256) void k_zbuild(const unsigned short* __restrict__ y2h,
        const int* __restrict__ rs, const int* __restrict__ epack,
        const float* __restrict__ btab, const float* __restrict__ sctab,
        const float* __restrict__ shtab, const float* __restrict__ epsv,
        int l, int mode, unsigned short* __restrict__ z, int N) {
    int gid = blockIdx.x * 256 + threadIdx.x;
    int n = gid >> 4;
    if (n >= N) return;
    int c = (gid & 15) << 3;
    float sc[8], sh[8];
    if (mode) {
        float4 a = *(const float4*)(sctab + c), b = *(const float4*)(sctab + c + 4);
        float4 d = *(const float4*)(shtab + c), e = *(const float4*)(shtab + c + 4);
        sc[0] = a.x; sc[1] = a.y; sc[2] = a.z; sc[3] = a.w;
        sc[4] = b.x; sc[5] = b.y; sc[6] = b.z; sc[7] = b.w;
        sh[0] = d.x; sh[1] = d.y; sh[2] = d.z; sh[3] = d.w;
        sh[4] = e.x; sh[5] = e.y; sh[6] = e.z; sh[7] = e.w;
    }
    int p0 = (n == 0) ? 0 : rs[n - 1];
    int p1 = rs[n];
    float ag[8] = {0.f, 0.f, 0.f, 0.f, 0.f, 0.f, 0.f, 0.f};
    int p = p0;
    for (; p + 2 <= p1; p += 2) {
        int rec0 = epack[p], rec1 = epack[p + 1];
        int s0 = rec0 & 0x3FFFF, s1 = rec1 & 0x3FFFF;
        int c0 = ((unsigned int)rec0) >> 18, c1 = ((unsigned int)rec1) >> 18;
        uv4 h0 = *(const uv4*)(y2h + (size_t)s0 * DD + c);
        uv4 h1 = *(const uv4*)(y2h + (size_t)s1 * DD + c);
        float bt0[8], bt1[8];
        {
            float4 a = *(const float4*)(btab + (size_t)c0 * DD + c);
            float4 b = *(const float4*)(btab + (size_t)c0 * DD + c + 4);
            bt0[0] = a.x; bt0[1] = a.y; bt0[2] = a.z; bt0[3] = a.w;
            bt0[4] = b.x; bt0[5] = b.y; bt0[6] = b.z; bt0[7] = b.w;
            float4 d = *(const float4*)(btab + (size_t)c1 * DD + c);
            float4 e = *(const float4*)(btab + (size_t)c1 * DD + c + 4);
            bt1[0] = d.x; bt1[1] = d.y; bt1[2] = d.z; bt1[3] = d.w;
            bt1[4] = e.x; bt1[5] = e.y; bt1[6] = e.z; bt1[7] = e.w;
        }
        edge_acc8(h0, bt0, sc, sh, mode, ag);
        edge_acc8(h1, bt1, sc, sh, mode, ag);
    }
    if (p < p1) {
        int rec = epack[p];
        int s0 = rec & 0x3FFFF;
        int c0 = ((unsigned int)rec) >> 18;
        uv4 h0 = *(const uv4*)(y2h + (size_t)s0 * DD + c);
        float bt0[8];
        float4 a = *(const float4*)(btab + (size_t)c0 * DD + c);
        float4 b = *(const float4*)(btab + (size_t)c0 * DD + c + 4);
        bt0[0] = a.x; bt0[1] = a.y; bt0[2] = a.z; bt0[3] = a.w;
        bt0[4] = b.x; bt0[5] = b.y; bt0[6] = b.z; bt0[7] = b.w;
        edge_acc8(h0, bt0, sc, sh, mode, ag);
    }
    float ep = 1.0f + epsv[l];
    uv4 sv = *(const uv4*)(y2h + (size_t)n * DD + c);
    uv4 o;
#pragma unroll
    for (int j = 0; j < 4; ++j) {
        float h0 = bf2f((unsigned short)(sv[j] & 0xFFFFu));
        float h1 = bf2f((unsigned short)(sv[j] >> 16));
        if (mode) {
            h0 = fmaxf(h0 * sc[2 * j] + sh[2 * j], 0.f);
            h1 = fmaxf(h1 * sc[2 * j + 1] + sh[2 * j + 1], 0.f);
        }
        o[j] = (unsigned int)f2bf(ep * h0 + ag[2 * j]) |
               ((unsigned int)f2bf(ep * h1 + ag[2 * j + 1]) << 16);
    }
    *(uv4*)(z + (size_t)n * DD + c) = o;
}

// ---------- Gram: per-block partial G = Z^T Z + colsum, direct stores (no atomics) ----------
__global__ __launch_bounds__(256) void k_gram(const unsigned short* __restrict__ z,
        float* __restrict__ shardG, float* __restrict__ csS, int N) {
    __shared__ uv4 zT[128 * 8];   // transposed tile [ch][8 granules of 8 rows], 16KB
    int tid = threadIdx.x;
    int lane = tid & 63, wave = tid >> 6, lq = lane >> 4, lr = lane & 15;
    int cg = tid & 15;
    float cs[8] = {0, 0, 0, 0, 0, 0, 0, 0};
    fv4 acc[2][8];
#pragma unroll
    for (int ti = 0; ti < 2; ++ti)
#pragma unroll
        for (int tj = 0; tj < 8; ++tj) acc[ti][tj] = (fv4){0.f, 0.f, 0.f, 0.f};

    int ntile = N >> 6;
    for (int t = blockIdx.x; t < ntile; t += GRAM_NB) {
        const unsigned short* zt0 = z + ((size_t)t << 6) * DD;
        __syncthreads();
#pragma unroll
        for (int i = 0; i < 2; ++i) {
            int rp = i * 16 + (tid >> 4);
            int r0 = rp * 2;
            uv4 a = *(const uv4*)(zt0 + (size_t)r0 * DD + cg * 8);
            uv4 b = *(const uv4*)(zt0 + (size_t)(r0 + 1) * DD + cg * 8);
            int g = rp >> 2;
            int eo = rp & 3;
#pragma unroll
            for (int j = 0; j < 4; ++j) {
                unsigned int lo0 = a[j] & 0xFFFFu, hi0 = a[j] >> 16;
                unsigned int lo1 = b[j] & 0xFFFFu, hi1 = b[j] >> 16;
                cs[2 * j] += bf2f((unsigned short)lo0) + bf2f((unsigned short)lo1);
                cs[2 * j + 1] += bf2f((unsigned short)hi0) + bf2f((unsigned short)hi1);
                int ch0 = cg * 8 + 2 * j, ch1 = ch0 + 1;
                int s0 = ch0 * 8 + (g ^ ((ch0 ^ (ch0 >> 3)) & 7));
                int s1 = ch1 * 8 + (g ^ ((ch1 ^ (ch1 >> 3)) & 7));
                ((unsigned int*)zT)[s0 * 4 + eo] = lo0 | (lo1 << 16);
                ((unsigned int*)zT)[s1 * 4 + eo] = hi0 | (hi1 << 16);
            }
        }
        __syncthreads();
#pragma unroll
        for (int ks = 0; ks < 2; ++ks) {
            bfv8 af[2], bfr[8];
#pragma unroll
            for (int ti = 0; ti < 2; ++ti) {
                int ch = wave * 32 + ti * 16 + lr;
                af[ti] = __builtin_bit_cast(bfv8, zT[ch * 8 + ((ks * 4 + lq) ^ ((ch ^ (ch >> 3)) & 7))]);
            }
#pragma unroll
            for (int tj = 0; tj < 8; ++tj) {
                int ch = tj * 16 + lr;
                bfr[tj] = __builtin_bit_cast(bfv8, zT[ch * 8 + ((ks * 4 + lq) ^ ((ch ^ (ch >> 3)) & 7))]);
            }
#pragma unroll
            for (int ti = 0; ti < 2; ++ti)
#pragma unroll
                for (int tj = 0; tj < 8; ++tj)
                    acc[ti][tj] = __builtin_amdgcn_mfma_f32_16x16x32_bf16(af[ti], bfr[tj], acc[ti][tj], 0, 0, 0);
        }
    }
    float* gsh = shardG + (size_t)blockIdx.x * (DD * DD);
#pragma unroll
    for (int ti = 0; ti < 2; ++ti) {
        int gi = wave * 32 + ti * 16 + lq * 4;
#pragma unroll
        for (int tj = 0; tj < 8; ++tj) {
            int gj = tj * 16 + lr;
#pragma unroll
            for (int r = 0; r < 4; ++r)
                gsh[(size_t)(gi + r) * DD + gj] = acc[ti][tj][r];
        }
    }
    __syncthreads();
    float* red = (float*)zT;
#pragma unroll
    for (int j = 0; j < 8; ++j) red[tid * 8 + j] = cs[j];
    __syncthreads();
    if (tid < 128) {
        int cgg = tid >> 3, j = tid & 7;
        float a = 0.f;
#pragma unroll
        for (int k = 0; k < 16; ++k) a += red[(k * 16 + cgg) * 8 + j];
        csS[blockIdx.x * DD + cgg * 8 + j] = a;
    }
}

// ---------- reduce G/cs shards to dense ----------
__global__ __launch_bounds__(256) void k_gred(const float* __restrict__ shardG,
        const float* __restrict__ csS, float* __restrict__ G, float* __restrict__ cs) {
    int idx = blockIdx.x * 256 + threadIdx.x;
    if (idx < DD * DD) {
        float a = 0.f;
#pragma unroll 8
        for (int s = 0; s < GRAM_NB; ++s) a += shardG[(size_t)s * DD * DD + idx];
        G[idx] = a;
    } else if (idx < DD * DD + DD) {
        int t = idx - DD * DD;
        float a = 0.f;
#pragma unroll 8
        for (int s = 0; s < GRAM_NB; ++s) a += csS[s * DD + t];
        cs[t] = a;
    }
}

// ---------- BN1 stats from Gram ----------
__global__ __launch_bounds__(128) void k_redG(const float* __restrict__ G,
        const float* __restrict__ cs, const unsigned short* __restrict__ W1l,
        const float* __restrict__ b1, const float* __restrict__ bng,
        const float* __restrict__ bnb, float invN,
        float* __restrict__ sc_out, float* __restrict__ sh_out) {
    __shared__ float wv[128];
    __shared__ float redA[128], redB[128];
    int j = blockIdx.x;
    int t = threadIdx.x;
    int kc = t >> 5, kk = t & 31;
    int o = kc * 8192 + j * 32 + kk;
    float w_t = bf2f(W1l[o]) + bf2f(W1l[32768 + o]);
    wv[t] = w_t;
    __syncthreads();
    const float4* Gr = (const float4*)(G + (size_t)t * DD);
    float d = 0.f;
#pragma unroll
    for (int i = 0; i < 32; ++i) {
        float4 g4 = Gr[i];
        d += g4.x * wv[i * 4] + g4.y * wv[i * 4 + 1] + g4.z * wv[i * 4 + 2] + g4.w * wv[i * 4 + 3];
    }
    redA[t] = w_t * d;
    redB[t] = cs[t] * w_t;
    __syncthreads();
    for (int off = 64; off > 0; off >>= 1) {
        if (t < off) { redA[t] += redA[t + off]; redB[t] += redB[t + off]; }
        __syncthreads();
    }
    if (t == 0) {
        float bj = b1[j];
        float csw = redB[0];
        float mean = csw * invN + bj;
        float ey2 = redA[0] * invN + 2.f * bj * csw * invN + bj * bj;
        float var = ey2 - mean * mean;
        float r = rsqrtf(var + 1e-5f);
        float sc = bng[j] * r;
        sc_out[j] = sc;
        sh_out[j] = bnb[j] - mean * sc + bj * sc;
    }
}

// ---------- fused GEMM: weights direct global->register (no weight LDS), 3 barriers ----------
__global__ __launch_bounds__(256, 3) void k_fgemm(const unsigned short* __restrict__ z,
        const unsigned short* __restrict__ W1l, const unsigned short* __restrict__ W2l,
        const float* __restrict__ sc1, const float* __restrict__ sh1,
        const float* __restrict__ bias2,
        unsigned short* __restrict__ y2h, float* __restrict__ shard, int N) {
    __shared__ uv4 smem[2048];           // 32KB
    uv4* zt = smem;                      // phase1: [64*16] 16KB
    uv4* at = smem;                      // phase2: [64*32] 32KB
    int tid = threadIdx.x;
    int row0 = blockIdx.x * 64;
    int wave = tid >> 6, lane = tid & 63, lq = lane >> 4, lr = lane & 15;
    int rbase = tid >> 4, gz = tid & 15;

    uv4 zr[4];
#pragma unroll
    for (int i = 0; i < 4; ++i)
        zr[i] = *(const uv4*)(z + (size_t)(row0 + i * 16 + rbase) * DD + gz * 8);
    const uv4* w1src = (const uv4*)W1l;
    uv4 wh[2][4], wl[2][4];
#pragma unroll
    for (int mc = 0; mc < 4; ++mc) {
        int col = wave * 64 + mc * 16 + lr;
        wh[0][mc] = w1src[(size_t)col * 4 + lq];
        wl[0][mc] = w1src[4096 + (size_t)col * 4 + lq];
    }
#pragma unroll
    for (int i = 0; i < 4; ++i) {
        int row = i * 16 + rbase;
        zt[row * 16 + (gz ^ (row & 15))] = zr[i];
    }
    __syncthreads();   // barrier 1/3

    fv4 acc1[4][4];
#pragma unroll
    for (int mc = 0; mc < 4; ++mc)
#pragma unroll
        for (int nr = 0; nr < 4; ++nr) acc1[mc][nr] = (fv4){0.f, 0.f, 0.f, 0.f};

#pragma unroll
    for (int kc = 0; kc < 4; ++kc) {
        const int cur = kc & 1, nxt = cur ^ 1;
        if (kc < 3) {
#pragma unroll
            for (int mc = 0; mc < 4; ++mc) {
                int col = wave * 64 + mc * 16 + lr;
                wh[nxt][mc] = w1src[(size_t)((kc + 1) * 256 + col) * 4 + lq];
                wl[nxt][mc] = w1src[4096 + (size_t)((kc + 1) * 256 + col) * 4 + lq];
            }
        }
        bfv8 zf[4];
#pragma unroll
        for (int nr = 0; nr < 4; ++nr) {
            int row = nr * 16 + lr;
            zf[nr] = __builtin_bit_cast(bfv8, zt[row * 16 + ((kc * 4 + lq) ^ (row & 15))]);
        }
#pragma unroll
        for (int mc = 0; mc < 4; ++mc)
#pragma unroll
            for (int nr = 0; nr < 4; ++nr) {
                acc1[mc][nr] = __builtin_amdgcn_mfma_f32_16x16x32_bf16(
                        __builtin_bit_cast(bfv8, wh[cur][mc]), zf[nr], acc1[mc][nr], 0, 0, 0);
                acc1[mc][nr] = __builtin_amdgcn_mfma_f32_16x16x32_bf16(
                        __builtin_bit_cast(bfv8, wl[cur][mc]), zf[nr], acc1[mc][nr], 0, 0, 0);
            }
    }
    __syncthreads();   // barrier 2/3

    const uv4* w2src = (const uv4*)W2l;
    uv4 w2h[2][2], w2l[2][2];
#pragma unroll
    for (int nb = 0; nb < 2; ++nb) {
        int col = wave * 32 + nb * 16 + lr;
        w2h[0][nb] = w2src[(size_t)col * 4 + lq];
        w2l[0][nb] = w2src[4096 + (size_t)col * 4 + lq];
    }

#pragma unroll
    for (int mc = 0; mc < 4; ++mc) {
        int ycol0 = wave * 64 + mc * 16 + lq * 4;
        float4 s4 = *(const float4*)(sc1 + ycol0);
        float4 h4 = *(const float4*)(sh1 + ycol0);
        int gg = wave * 8 + mc * 2 + (lq >> 1);
#pragma unroll
        for (int nr = 0; nr < 4; ++nr) {
            int zrow = nr * 16 + lr;
            float v0 = fmaxf(acc1[mc][nr][0] * s4.x + h4.x, 0.f);
            float v1 = fmaxf(acc1[mc][nr][1] * s4.y + h4.y, 0.f);
            float v2 = fmaxf(acc1[mc][nr][2] * s4.z + h4.z, 0.f);
            float v3 = fmaxf(acc1[mc][nr][3] * s4.w + h4.w, 0.f);
            uint2 pk;
            pk.x = (unsigned int)f2bf(v0) | ((unsigned int)f2bf(v1) << 16);
            pk.y = (unsigned int)f2bf(v2) | ((unsigned int)f2bf(v3) << 16);
            int gs = gg ^ (zrow & 15);
            ((uint2*)at)[(zrow * 32 + gs) * 2 + (lq & 1)] = pk;
        }
    }
    __syncthreads();   // barrier 3/3

    fv4 acc2[4][2];
#pragma unroll
    for (int m = 0; m < 4; ++m) { acc2[m][0] = (fv4){0.f,0.f,0.f,0.f}; acc2[m][1] = (fv4){0.f,0.f,0.f,0.f}; }

#pragma unroll
    for (int kc = 0; kc < 8; ++kc) {
        const int cur = kc & 1, nxt = cur ^ 1;
        if (kc < 7) {
#pragma unroll
            for (int nb = 0; nb < 2; ++nb) {
                int col = wave * 32 + nb * 16 + lr;
                w2h[nxt][nb] = w2src[(size_t)((kc + 1) * 128 + col) * 4 + lq];
                w2l[nxt][nb] = w2src[4096 + (size_t)((kc + 1) * 128 + col) * 4 + lq];
            }
        }
        bfv8 a[4];
#pragma unroll
        for (int m = 0; m < 4; ++m) {
            int row = m * 16 + lr;
            a[m] = __builtin_bit_cast(bfv8, at[row * 32 + ((kc * 4 + lq) ^ (row & 15))]);
        }
#pragma unroll
        for (int m = 0; m < 4; ++m)
#pragma unroll
            for (int nb = 0; nb < 2; ++nb) {
                acc2[m][nb] = __builtin_amdgcn_mfma_f32_16x16x32_bf16(
                        a[m], __builtin_bit_cast(bfv8, w2h[cur][nb]), acc2[m][nb], 0, 0, 0);
                acc2[m][nb] = __builtin_amdgcn_mfma_f32_16x16x32_bf16(
                        a[m], __builtin_bit_cast(bfv8, w2l[cur][nb]), acc2[m][nb], 0, 0, 0);
            }
    }

    float bv[2], s[2], q[2];
#pragma unroll
    for (int nb = 0; nb < 2; ++nb) {
        bv[nb] = bias2[wave * 32 + nb * 16 + lr];
        s[nb] = 0.f; q[nb] = 0.f;
    }
#pragma unroll
    for (int m = 0; m < 4; ++m)
#pragma unroll
        for (int nb = 0; nb < 2; ++nb) {
            int col = wave * 32 + nb * 16 + lr;
#pragma unroll
            for (int r = 0; r < 4; ++r) {
                float v = acc2[m][nb][r] + bv[nb];
                unsigned short ub = f2bf(v);
                float vr = bf2f(ub);
                int row = row0 + m * 16 + lq * 4 + r;
                y2h[(size_t)row * DD + col] = ub;
                s[nb] += vr; q[nb] += vr * vr;
            }
        }
#pragma unroll
    for (int nb = 0; nb < 2; ++nb) {
        s[nb] += __shfl_xor(s[nb], 16); s[nb] += __shfl_xor(s[nb], 32);
        q[nb] += __shfl_xor(q[nb], 16); q[nb] += __shfl_xor(q[nb], 32);
    }
    if (lane < 16) {
        int shb = (blockIdx.x & (NSHARD - 1)) * 256;
#pragma unroll
        for (int nb = 0; nb < 2; ++nb) {
            int col = wave * 32 + nb * 16 + lr;
            atomicAdd(shard + shb + col, s[nb]);
            atomicAdd(shard + shb + 128 + col, q[nb]);
        }
    }
}

// ---------- final: out = relu(bn2(y2h)) -> f32 ----------
__global__ __launch_bounds__(256) void k_bnfinal(const unsigned short* __restrict__ y2h,
        const float* __restrict__ sc2, const float* __restrict__ sh2,
        float* __restrict__ out, int N) {
    size_t base = ((size_t)blockIdx.x * 256 + threadIdx.x) * 4;
    if (base >= (size_t)N * DD) return;
    int c = (int)(base & (DD - 1));
    ushort4 v = *(const ushort4*)(y2h + base);
    float4 s = *(const float4*)(sc2 + c);
    float4 t = *(const float4*)(sh2 + c);
    float4 o;
    o.x = fmaxf(bf2f(v.x) * s.x + t.x, 0.f);
    o.y = fmaxf(bf2f(v.y) * s.y + t.y, 0.f);
    o.z = fmaxf(bf2f(v.z) * s.z + t.z, 0.f);
    o.w = fmaxf(bf2f(v.w) * s.w + t.w, 0.f);
    *(float4*)(out + base) = o;
}

extern "C" void kernel_launch(void* const* d_in, const int* in_sizes, int n_in,
                              void* d_out, int out_size, void* d_ws, size_t ws_size,
                              hipStream_t stream) {
    const int* x = (const int*)d_in[0];
    const int* ei = (const int*)d_in[1];
    const int* ea = (const int*)d_in[2];
    const float* atom_emb = (const float*)d_in[3];
    const float* bond_emb = (const float*)d_in[4];
    const float* W1 = (const float*)d_in[5];
    const float* b1 = (const float*)d_in[6];
    const float* bn1_g = (const float*)d_in[7];
    const float* bn1_b = (const float*)d_in[8];
    const float* W2 = (const float*)d_in[9];
    const float* b2 = (const float*)d_in[10];
    const float* epsv = (const float*)d_in[11];
    const float* obn_g = (const float*)d_in[12];
    const float* obn_b = (const float*)d_in[13];
    int N = in_sizes[0] / NF_ATOM;   // 200000 (divisible by 64)
    int E = in_sizes[1] / 2;

    char* wsb = (char*)d_ws;
    unsigned short* y2h = (unsigned short*)wsb;                        // N*128 bf16
    unsigned short* zb = (unsigned short*)(wsb + (size_t)N * 256);     // N*128 bf16
    int* epack = (int*)(wsb + (size_t)N * 512);                        // E int
    unsigned short* w1t = (unsigned short*)(wsb + (size_t)N * 512 + (size_t)E * 4);  // 5*65536
    unsigned short* w2t = w1t + 327680;                                // 5*65536
    float* btab = (float*)((char*)w2t + 655360);                       // 5*216*128 f32
    float* sc1 = btab + NLAYER * NCODE * DD;                           // 256
    float* sh1 = sc1 + 256;
    float* sc2 = sh1 + 256;                                            // 128
    float* sh2 = sc2 + 128;
    float* G = sh2 + 128;                                              // 16384
    float* cs = G + DD * DD;                                           // 128
    float* shardG = cs + DD;                                           // 256*16384 (reused per layer)
    float* csS = shardG + (size_t)GRAM_NB * DD * DD;                   // 256*128
    float* shard2 = csS + GRAM_NB * DD;                                // 5 * 32*256 (zeroed)
    size_t zero_f = (size_t)NLAYER * NSHARD * 256;
    int* rsarr = (int*)(shard2 + (size_t)NLAYER * NSHARD * 256);       // N+1
    int* bsum = rsarr + (N + 1);
    int* boff = bsum + 256;
    float invN = 1.0f / (float)N;
    int nbk = (N + 1023) / 1024;

    k_wconv<<<1280, 256, 0, stream>>>(W1, W2, w1t, w2t);
    k_bsumtab<<<(NLAYER * NCODE * DD + 255) / 256, 256, 0, stream>>>(bond_emb, btab);
    hipMemsetAsync(rsarr, 0, ((size_t)N + 1) * 4, stream);
    hipMemsetAsync(shard2, 0, zero_f * sizeof(float), stream);
    k_deg<<<(E + 255) / 256, 256, 0, stream>>>(ei, rsarr, E);
    k_bsum<<<nbk, 256, 0, stream>>>(rsarr, bsum, N);
    k_bscan<<<1, 256, 0, stream>>>(bsum, boff, nbk);
    k_csr<<<nbk, 256, 0, stream>>>(rsarr, boff, rsarr, N, E);
    k_scatter<<<(E + 255) / 256, 256, 0, stream>>>(ei, ea, rsarr, epack, E);
    k_atom<<<(N * 32 + 255) / 256, 256, 0, stream>>>(x, atom_emb, y2h, N);

    int gb = N / 64;
    for (int l = 0; l < NLAYER; ++l) {
        float* sh2d = shard2 + (size_t)l * NSHARD * 256;
        k_zbuild<<<(N * 16 + 255) / 256, 256, 0, stream>>>(y2h, rsarr, epack,
                btab + (size_t)l * NCODE * DD, sc2, sh2, epsv, l, (l == 0) ? 0 : 1, zb, N);
        k_gram<<<GRAM_NB, 256, 0, stream>>>(zb, shardG, csS, N);
        k_gred<<<(DD * DD + DD + 255) / 256, 256, 0, stream>>>(shardG, csS, G, cs);
        k_redG<<<HH, 128, 0, stream>>>(G, cs, w1t + (size_t)l * 65536, b1 + l * HH,
                bn1_g + l * HH, bn1_b + l * HH, invN, sc1, sh1);
        k_fgemm<<<gb, 256, 0, stream>>>(zb, w1t + (size_t)l * 65536, w2t + (size_t)l * 65536,
                sc1, sh1, b2 + l * DD, y2h, sh2d, N);
        k_red<<<1, 128, 0, stream>>>(sh2d, 128, obn_g + l * DD, obn_b + l * DD, invN, sc2, sh2);
    }
    k_bnfinal<<<(int)(((size_t)N * DD / 4 + 255) / 256), 256, 0, stream>>>(
            y2h, sc2, sh2, (float*)d_out, N);
}